// Round 6
// baseline (511.821 us; speedup 1.0000x reference)
//
#include <hip/hip_runtime.h>

typedef unsigned short u16;
typedef __bf16 bf16x8 __attribute__((ext_vector_type(8)));
typedef float f32x4 __attribute__((ext_vector_type(4)));
typedef unsigned short u16x8 __attribute__((ext_vector_type(8)));

#define GA 256  // edge-chunk blocks for count/partition (must match in both passes)

static __device__ __forceinline__ float bf2f(u16 u) {
    return __uint_as_float(((unsigned)u) << 16);
}
static __device__ __forceinline__ u16 f2bf(float f) {
    unsigned u = __float_as_uint(f);
    unsigned r = (u + 0x7FFFu + ((u >> 16) & 1u)) >> 16;
    return (u16)r;
}

// ---- edge_index word-stride detection: int32-packed (1) vs int64-as-2-words (2)
__global__ void detect_kernel(const int* __restrict__ ei, int* __restrict__ flag) {
    if (blockIdx.x == 0 && threadIdx.x == 0) {
        int zc = 0;
        for (int t = 0; t < 64; ++t) zc += (ei[2 * t + 1] == 0) ? 1 : 0;
        *flag = (zc >= 60) ? 2 : 1;
    }
}
static __device__ __forceinline__ int ld_idx(const int* ei, int pos, int st, int N) {
    int v = ei[(size_t)pos * (size_t)st];
    return v < 0 ? 0 : (v >= N ? N - 1 : v);
}

// ================= generic exclusive scan over int array (length M) ==========
#define SCHUNK 4096
__global__ void xscan_reduce(const int* __restrict__ arr, int* __restrict__ bsum, int M) {
    __shared__ int sdata[256];
    int t = threadIdx.x;
    int base = blockIdx.x * SCHUNK + t * 16;
    int s = 0;
#pragma unroll
    for (int j = 0; j < 16; ++j) { int i = base + j; s += (i < M) ? arr[i] : 0; }
    sdata[t] = s;
    __syncthreads();
    for (int o = 128; o > 0; o >>= 1) {
        if (t < o) sdata[t] += sdata[t + o];
        __syncthreads();
    }
    if (t == 0) bsum[blockIdx.x] = sdata[0];
}
__global__ void scan_mid_kernel(int* __restrict__ bsum, int nb) {
    if (threadIdx.x == 0 && blockIdx.x == 0) {
        int run = 0;
        for (int b = 0; b < nb; ++b) { int v = bsum[b]; bsum[b] = run; run += v; }
    }
}
__global__ void xscan_final(int* __restrict__ arr, const int* __restrict__ bsum, int M) {
    __shared__ int sdata[256];
    int t = threadIdx.x;
    int base = blockIdx.x * SCHUNK + t * 16;
    int v[16];
    int s = 0;
#pragma unroll
    for (int j = 0; j < 16; ++j) {
        int i = base + j;
        v[j] = (i < M) ? arr[i] : 0;
        s += v[j];
    }
    sdata[t] = s;
    __syncthreads();
    for (int o = 1; o < 256; o <<= 1) {
        int add = (t >= o) ? sdata[t - o] : 0;
        __syncthreads();
        sdata[t] += add;
        __syncthreads();
    }
    int excl = (t == 0) ? 0 : sdata[t - 1];
    int off = bsum[blockIdx.x] + excl;
#pragma unroll
    for (int j = 0; j < 16; ++j) {
        int i = base + j;
        if (i < M) { arr[i] = off; off += v[j]; }
    }
}

// ================= radix partition by dst bucket (LDS cursors only) ==========
__global__ __launch_bounds__(256) void partition_kernel(const int* __restrict__ ei,
                                                        const int* __restrict__ flag,
                                                        const int* __restrict__ offs,
                                                        unsigned* __restrict__ ebuf, int E,
                                                        int N) {
    __shared__ int cur[1024];
    const int K = (N + 127) >> 7;
    const int bh = blockIdx.x;
    for (int k = threadIdx.x; k < K; k += 256) cur[k] = offs[(size_t)k * GA + bh];
    __syncthreads();
    const int st = *flag;
    const int chunk = (E + GA - 1) / GA;
    const int lo = bh * chunk;
    const int hi = (lo + chunk < E) ? lo + chunk : E;
    for (int j = lo + (int)threadIdx.x; j < hi; j += 256) {
        int d = ld_idx(ei, E + j, st, N);
        int s = ld_idx(ei, j, st, N);
        int pos = atomicAdd(&cur[d >> 7], 1);
        ebuf[pos] = ((unsigned)(d & 127) << 25) | (unsigned)s;
    }
}

// ================= per-bucket CSR build (LDS atomics only) ===================
__global__ __launch_bounds__(256) void csr_build(const unsigned* __restrict__ ebuf,
                                                 const int* __restrict__ offs,
                                                 int* __restrict__ rowptr,
                                                 int* __restrict__ col, int E, int N, int ET) {
    __shared__ int dg[128];
    __shared__ int sc[128];
    __shared__ int cur[128];
    const int K = (N + 127) >> 7;
    const int k = blockIdx.x;
    const int base = k << 7;
    const int nn = (N - base < 128) ? (N - base) : 128;
    const int e0 = offs[(size_t)k * GA];
    const int e1 = (k + 1 < K) ? offs[(size_t)(k + 1) * GA] : E;
    for (int t = threadIdx.x; t < 128; t += 256) dg[t] = 0;
    __syncthreads();
    for (int e = e0 + (int)threadIdx.x; e < e1; e += 256)
        atomicAdd(&dg[ebuf[e] >> 25], 1);
    __syncthreads();
    const int t = threadIdx.x;
    int v = 0;
    if (t < 128) {
        v = (t < nn) ? dg[t] + 1 : 0;  // +1 self loop
        sc[t] = v;
    }
    __syncthreads();
    for (int o = 1; o < 128; o <<= 1) {
        int add = 0;
        if (t < 128 && t >= o) add = sc[t - o];
        __syncthreads();
        if (t < 128) sc[t] += add;
        __syncthreads();
    }
    const int colbase = e0 + base;
    if (t < nn) {
        int rp = colbase + sc[t] - v;
        rowptr[base + t] = rp;
        col[rp] = base + t;  // self loop first
        cur[t] = rp + 1;
    }
    if (k == 0 && t == 0) rowptr[N] = ET;
    __syncthreads();
    for (int e = e0 + (int)threadIdx.x; e < e1; e += 256) {
        unsigned p = ebuf[e];
        int pos = atomicAdd(&cur[p >> 25], 1);
        col[pos] = (int)(p & 0x1FFFFFFu);
    }
}

// ---------------- fused GEMM: C[M,NC] = A[M,128] @ W[128,NC]
// A (when !AF32) and C (when EPI!=2) are SLICE-MAJOR bf16:
//   elem(node, feat) at buf[(feat>>4)*(M*16) + node*16 + (feat&15)]
// so that each 16-feature slice is a contiguous M*32B panel (L2-residency for
// the sliced aggregation). AF32 path (external x) stays row-major f32.
template <int NC, bool AF32, int EPI, bool HIST>
__global__ __launch_bounds__(256) void gemm_fused(
    const void* __restrict__ Ap, const float* __restrict__ W, u16* __restrict__ Cout, int M,
    const float* __restrict__ av_s, const float* __restrict__ av_d, float* __restrict__ ssrc,
    float* __restrict__ sdst, const float* __restrict__ bl, float* __restrict__ outp,
    const int* __restrict__ ei, const int* __restrict__ flag, int* __restrict__ cntmat, int E,
    int ET, int N, int G1) {
    if (HIST && (int)blockIdx.x >= G1) {
        __shared__ int cnt[1024];
        const int bh = (int)blockIdx.x - G1;
        const int nga = (int)gridDim.x - G1;  // == GA
        const int K = (N + 127) >> 7;
        for (int k = threadIdx.x; k < K; k += 256) cnt[k] = 0;
        __syncthreads();
        const int st = *flag;
        const int chunk = (E + nga - 1) / nga;
        const int lo = bh * chunk;
        const int hi = (lo + chunk < E) ? lo + chunk : E;
        for (int j = lo + (int)threadIdx.x; j < hi; j += 256) {
            int d = ld_idx(ei, E + j, st, N);
            atomicAdd(&cnt[d >> 7], 1);
        }
        __syncthreads();
        for (int k = threadIdx.x; k < K; k += 256) cntmat[(size_t)k * nga + bh] = cnt[k];
        return;
    }
    const int lane = threadIdx.x & 63;
    const int quad = lane >> 4;
    const int r = lane & 15;
    const int gw = (blockIdx.x * 256 + threadIdx.x) >> 6;
    const int nw = G1 * 4;
    const size_t SL = (size_t)M * 16;  // slice panel stride (elements)

    bf16x8 bf[NC / 16][4];
#pragma unroll
    for (int nt = 0; nt < NC / 16; ++nt)
#pragma unroll
        for (int kk = 0; kk < 4; ++kk) {
            union { bf16x8 v; u16 s[8]; } u;
#pragma unroll
            for (int j = 0; j < 8; ++j)
                u.s[j] = f2bf(W[(size_t)(kk * 32 + quad * 8 + j) * NC + nt * 16 + r]);
            bf[nt][kk] = u.v;
        }
    float avs[NC / 16], avd[NC / 16], blv[NC / 16];
    if (EPI == 1) {
#pragma unroll
        for (int nt = 0; nt < NC / 16; ++nt) {
            avs[nt] = av_s[nt * 16 + r];
            avd[nt] = av_d[nt * 16 + r];
        }
    }
    if (EPI == 2) {
#pragma unroll
        for (int nt = 0; nt < NC / 16; ++nt) blv[nt] = bl[nt * 16 + r];
    }

    const int ntiles = (M + 15) >> 4;
    for (int t = gw; t < ntiles; t += nw) {
        const int row0 = t << 4;
        bf16x8 af[4];
        if (AF32) {
            const float* arow = (const float*)Ap + (size_t)(row0 + r) * 128;
#pragma unroll
            for (int kk = 0; kk < 4; ++kk) {
                f32x4 f0 = *reinterpret_cast<const f32x4*>(arow + kk * 32 + quad * 8);
                f32x4 f1 = *reinterpret_cast<const f32x4*>(arow + kk * 32 + quad * 8 + 4);
                union { bf16x8 v; u16 s[8]; } u;
#pragma unroll
                for (int j = 0; j < 4; ++j) { u.s[j] = f2bf(f0[j]); u.s[4 + j] = f2bf(f1[j]); }
                af[kk] = u.v;
            }
        } else {
            const u16* abase = (const u16*)Ap;
#pragma unroll
            for (int kk = 0; kk < 4; ++kk) {
                const int fb = kk * 32 + quad * 8;  // fb&15 in {0,8}: stays in one slice
                af[kk] = *reinterpret_cast<const bf16x8*>(
                    abase + (size_t)(fb >> 4) * SL + (size_t)(row0 + r) * 16 + (fb & 15));
            }
        }
        f32x4 acc[NC / 16];
#pragma unroll
        for (int nt = 0; nt < NC / 16; ++nt) acc[nt] = (f32x4){0.f, 0.f, 0.f, 0.f};
#pragma unroll
        for (int kk = 0; kk < 4; ++kk)
#pragma unroll
            for (int nt = 0; nt < NC / 16; ++nt)
                acc[nt] = __builtin_amdgcn_mfma_f32_16x16x32_bf16(af[kk], bf[nt][kk],
                                                                  acc[nt], 0, 0, 0);
        if (EPI != 2) {
            // slice-major C store: slice == nt, within-slice feat == r
#pragma unroll
            for (int nt = 0; nt < NC / 16; ++nt)
#pragma unroll
                for (int reg = 0; reg < 4; ++reg)
                    Cout[(size_t)nt * SL + (size_t)(row0 + quad * 4 + reg) * 16 + r] =
                        f2bf(acc[nt][reg]);
        }
        if (EPI == 1) {
            float ps[4] = {0.f, 0.f, 0.f, 0.f}, pd[4] = {0.f, 0.f, 0.f, 0.f};
#pragma unroll
            for (int nt = 0; nt < NC / 16; ++nt)
#pragma unroll
                for (int reg = 0; reg < 4; ++reg) {
                    ps[reg] += acc[nt][reg] * avs[nt];
                    pd[reg] += acc[nt][reg] * avd[nt];
                }
#pragma unroll
            for (int o = 1; o < 16; o <<= 1)
#pragma unroll
                for (int reg = 0; reg < 4; ++reg) {
                    ps[reg] += __shfl_xor(ps[reg], o);
                    pd[reg] += __shfl_xor(pd[reg], o);
                }
            if (r == 0) {
#pragma unroll
                for (int reg = 0; reg < 4; ++reg) {
                    ssrc[row0 + quad * 4 + reg] = ps[reg];
                    sdst[row0 + quad * 4 + reg] = pd[reg];
                }
            }
        }
        if (EPI == 2) {
#pragma unroll
            for (int reg = 0; reg < 4; ++reg) {
                float v[NC / 16];
                float m = -3.4e38f;
#pragma unroll
                for (int nt = 0; nt < NC / 16; ++nt) {
                    v[nt] = acc[nt][reg] + blv[nt];
                    m = fmaxf(m, v[nt]);
                }
#pragma unroll
                for (int o = 1; o < 16; o <<= 1) m = fmaxf(m, __shfl_xor(m, o));
                float s = 0.f;
#pragma unroll
                for (int nt = 0; nt < NC / 16; ++nt) s += __expf(v[nt] - m);
#pragma unroll
                for (int o = 1; o < 16; o <<= 1) s += __shfl_xor(s, o);
                float L = __logf(s);
                const size_t rb = (size_t)(row0 + quad * 4 + reg) * NC;
#pragma unroll
                for (int nt = 0; nt < NC / 16; ++nt)
                    outp[rb + nt * 16 + r] = v[nt] - m - L;
            }
        }
    }
}

// ---------------- per-edge softmax weights + per-node 1/denom -----------------
// 16-lane group per dst node. wv[e] = bf16-truncated exp(leaky(score)) --
// truncated value also summed into denom so normalization cancels rounding.
__global__ __launch_bounds__(256) void wcompute(const int* __restrict__ rowptr,
                                                const int* __restrict__ col,
                                                const float* __restrict__ ssrc,
                                                const float* __restrict__ sdst,
                                                u16* __restrict__ wv,
                                                float* __restrict__ rdenom, int N) {
    const int lane = threadIdx.x & 63;
    const int gwave = (blockIdx.x * 256 + threadIdx.x) >> 6;
    const int grp = lane >> 4;
    const int ln = lane & 15;
    const int i = gwave * 4 + grp;
    if (i >= N) return;
    const int start = rowptr[i], end = rowptr[i + 1];
    const float sd = sdst[i];
    float sm = 0.f;
    for (int e = start + ln; e < end; e += 16) {
        float sc = ssrc[col[e]] + sd;
        sc = sc > 0.f ? sc : 0.2f * sc;
        float w = __expf(fminf(sc, 60.f));
        unsigned u = __float_as_uint(w) & 0xFFFF0000u;
        wv[e] = (u16)(u >> 16);
        sm += __uint_as_float(u);
    }
#pragma unroll
    for (int o = 1; o < 16; o <<= 1) sm += __shfl_xor(sm, o);
    if (ln == 0) rdenom[i] = 1.f / sm;
}

// ---------------- XCD-pinned feature-sliced aggregation ----------------------
// slice = blockIdx&7 -> (round-robin block->XCD) slice s runs on XCD s only;
// its 3.2MB hT panel is L2-resident, so the random row gather is an L2 hit.
// 16-lane group per node: hi = ln>>3 picks edge parity (2 edges/step),
// f2 = (ln&7)*2 picks the feature pair; halves combined via shfl_xor(8).
// MODE 1: out = relu(acc/sm + b).  MODE 2: out = acc/sm + b + skip.
template <int MODE>
__global__ __launch_bounds__(256) void agg_sliced(
    const int* __restrict__ rowptr, const int* __restrict__ col,
    const u16* __restrict__ wv, const float* __restrict__ rdenom,
    const u16* __restrict__ hT, const float* __restrict__ b, const u16* __restrict__ skipT,
    u16* __restrict__ outT, int N) {
    const int slice = blockIdx.x & 7;
    const int wb = blockIdx.x >> 3;
    const int lane = threadIdx.x & 63;
    const int gwave = (wb * 256 + (int)threadIdx.x) >> 6;
    const int grp = lane >> 4;
    const int ln = lane & 15;
    const int i = gwave * 4 + grp;
    if (i >= N) return;
    const int start = rowptr[i], end = rowptr[i + 1];
    const int hi = ln >> 3;
    const int f2 = (ln & 7) * 2;
    const size_t SL = (size_t)N * 16;
    const u16* hs = hT + (size_t)slice * SL;

    float a0 = 0.f, a1 = 0.f;
    int e = start;
    for (; e + 8 <= end; e += 8) {
        int c0 = col[e + hi], c1 = col[e + 2 + hi], c2 = col[e + 4 + hi],
            c3 = col[e + 6 + hi];
        u16 w0 = wv[e + hi], w1 = wv[e + 2 + hi], w2 = wv[e + 4 + hi], w3 = wv[e + 6 + hi];
        unsigned r0 = *reinterpret_cast<const unsigned*>(hs + (size_t)c0 * 16 + f2);
        unsigned r1 = *reinterpret_cast<const unsigned*>(hs + (size_t)c1 * 16 + f2);
        unsigned r2 = *reinterpret_cast<const unsigned*>(hs + (size_t)c2 * 16 + f2);
        unsigned r3 = *reinterpret_cast<const unsigned*>(hs + (size_t)c3 * 16 + f2);
        float fw0 = bf2f(w0), fw1 = bf2f(w1), fw2 = bf2f(w2), fw3 = bf2f(w3);
        a0 += fw0 * bf2f((u16)(r0 & 0xFFFFu)) + fw1 * bf2f((u16)(r1 & 0xFFFFu));
        a1 += fw0 * bf2f((u16)(r0 >> 16)) + fw1 * bf2f((u16)(r1 >> 16));
        a0 += fw2 * bf2f((u16)(r2 & 0xFFFFu)) + fw3 * bf2f((u16)(r3 & 0xFFFFu));
        a1 += fw2 * bf2f((u16)(r2 >> 16)) + fw3 * bf2f((u16)(r3 >> 16));
    }
    for (; e + 2 <= end; e += 2) {
        int c0 = col[e + hi];
        u16 w0 = wv[e + hi];
        unsigned r0 = *reinterpret_cast<const unsigned*>(hs + (size_t)c0 * 16 + f2);
        float fw0 = bf2f(w0);
        a0 += fw0 * bf2f((u16)(r0 & 0xFFFFu));
        a1 += fw0 * bf2f((u16)(r0 >> 16));
    }
    if (e < end && hi == 0) {  // odd tail: half-lanes only
        int c0 = col[e];
        float fw0 = bf2f(wv[e]);
        unsigned r0 = *reinterpret_cast<const unsigned*>(hs + (size_t)c0 * 16 + f2);
        a0 += fw0 * bf2f((u16)(r0 & 0xFFFFu));
        a1 += fw0 * bf2f((u16)(r0 >> 16));
    }
    a0 += __shfl_xor(a0, 8);
    a1 += __shfl_xor(a1, 8);
    if (hi == 0) {
        const float rd = rdenom[i];
        float v0 = a0 * rd + b[slice * 16 + f2];
        float v1 = a1 * rd + b[slice * 16 + f2 + 1];
        if (MODE == 1) {
            v0 = v0 > 0.f ? v0 : 0.f;
            v1 = v1 > 0.f ? v1 : 0.f;
        } else {
            const u16* sk = skipT + (size_t)slice * SL + (size_t)i * 16 + f2;
            v0 += bf2f(sk[0]);
            v1 += bf2f(sk[1]);
        }
        unsigned o = ((unsigned)f2bf(v1) << 16) | (unsigned)f2bf(v0);
        *reinterpret_cast<unsigned*>(outT + (size_t)slice * SL + (size_t)i * 16 + f2) = o;
    }
}

// ---------------- echo edge_index as f32 (output 1)
__global__ void copy_ei_kernel(const int* __restrict__ ei, const int* __restrict__ flag,
                               float* __restrict__ out, int n, int N) {
    int j = blockIdx.x * 256 + threadIdx.x;
    if (j < n) out[j] = (float)ld_idx(ei, j, *flag, N);
}

extern "C" void kernel_launch(void* const* d_in, const int* in_sizes, int n_in, void* d_out,
                              int out_size, void* d_ws, size_t ws_size, hipStream_t stream) {
    int ix = 0, iei = 1;
    if (in_sizes[0] < in_sizes[1]) { ix = 1; iei = 0; }
    const float* x = (const float*)d_in[ix];
    const int* ei = (const int*)d_in[iei];
    const float* W1 = (const float*)d_in[2];
    const float* a1s = (const float*)d_in[3];
    const float* a1d = (const float*)d_in[4];
    const float* b1 = (const float*)d_in[5];
    const float* W2 = (const float*)d_in[6];
    const float* a2s = (const float*)d_in[7];
    const float* a2d = (const float*)d_in[8];
    const float* b2 = (const float*)d_in[9];
    const float* Wl = (const float*)d_in[10];
    const float* bl = (const float*)d_in[11];

    const int N = in_sizes[ix] / 128;
    const int E = (out_size - N * 64) / 2;  // out = [logp N*64 | edge_index 2E], f32
    const int ET = E + N;
    const int K = (N + 127) >> 7;   // dst buckets of 128 nodes
    const int Mscan = K * GA;       // cntmat elements

    char* ws = (char*)d_ws;
    size_t off = 0;
    auto alloc = [&](size_t bytes) {
        void* p = ws + off;
        off += (bytes + 255) & ~(size_t)255;
        return p;
    };
    u16* h = (u16*)alloc((size_t)N * 128 * 2);   // slice-major gemm out / gather source
    u16* h1 = (u16*)alloc((size_t)N * 128 * 2);  // slice-major layer-1 activation (skip)
    u16* o2 = (u16*)alloc((size_t)N * 128 * 2);  // slice-major layer-2 out
    float* ssrc = (float*)alloc((size_t)N * 4);
    float* sdst = (float*)alloc((size_t)N * 4);
    int* eflag = (int*)alloc(256);
    int* cntmat = (int*)alloc((size_t)Mscan * 4);  // per-(bucket,block) counts -> offsets
    int* rowptr = (int*)alloc((size_t)(N + 1) * 4);
    int* bsum = (int*)alloc(4096);
    int* colv = (int*)alloc((size_t)ET * 4);
    u16* wv = (u16*)alloc((size_t)ET * 2);        // per-edge bf16 softmax weight
    float* rdenom = (float*)alloc((size_t)N * 4); // per-node 1/denominator
    // ebuf (partitioned packed edges, E u32) aliases h1: last read in csr_build,
    // h1 first written by agg_sliced<1> afterwards (stream-ordered).
    unsigned* ebuf = (unsigned*)h1;

    float* out_logp = (float*)d_out;
    float* out_ei = out_logp + (size_t)N * 64;

    dim3 blk(256);
    const int ngrid4 = (N + 15) / 16;  // 16-lane group per node, 16 nodes/block
    const int nbx = (Mscan + SCHUNK - 1) / SCHUNK;
    const int G1 = 512;  // gemm blocks in fused gemm+count

    detect_kernel<<<1, 64, 0, stream>>>(ei, eflag);

    // ---- layer-1 GEMM (+scores epilogue) fused with LDS bucket-count ----
    gemm_fused<128, true, 1, true><<<G1 + GA, blk, 0, stream>>>(
        x, W1, h, N, a1s, a1d, ssrc, sdst, nullptr, nullptr, ei, eflag, cntmat, E, ET, N, G1);

    // ---- exclusive scan of cntmat -> per-(bucket,block) offsets ----
    xscan_reduce<<<nbx, blk, 0, stream>>>(cntmat, bsum, Mscan);
    scan_mid_kernel<<<1, 64, 0, stream>>>(bsum, nbx);
    xscan_final<<<nbx, blk, 0, stream>>>(cntmat, bsum, Mscan);

    // ---- radix partition + per-bucket CSR build (LDS atomics only) ----
    partition_kernel<<<GA, blk, 0, stream>>>(ei, eflag, cntmat, ebuf, E, N);
    csr_build<<<K, blk, 0, stream>>>(ebuf, cntmat, rowptr, colv, E, N, ET);

    // ---- layer 1: weights+denoms, then sliced aggregation (+relu/bias) ----
    wcompute<<<ngrid4, blk, 0, stream>>>(rowptr, colv, ssrc, sdst, wv, rdenom, N);
    agg_sliced<1><<<ngrid4 * 8, blk, 0, stream>>>(rowptr, colv, wv, rdenom, h, b1, nullptr,
                                                  h1, N);

    // ---- layer 2 ----
    gemm_fused<128, false, 1, false><<<G1, blk, 0, stream>>>(
        h1, W2, h, N, a2s, a2d, ssrc, sdst, nullptr, nullptr, nullptr, nullptr, nullptr, 0, 0,
        N, G1);
    wcompute<<<ngrid4, blk, 0, stream>>>(rowptr, colv, ssrc, sdst, wv, rdenom, N);
    agg_sliced<2><<<ngrid4 * 8, blk, 0, stream>>>(rowptr, colv, wv, rdenom, h, b2, h1, o2, N);

    // ---- final linear with fused log_softmax ----
    gemm_fused<64, false, 2, false><<<G1, blk, 0, stream>>>(
        o2, Wl, nullptr, N, nullptr, nullptr, nullptr, nullptr, bl, out_logp, nullptr, nullptr,
        nullptr, 0, 0, N, G1);

    copy_ei_kernel<<<(2 * E + 255) / 256, blk, 0, stream>>>(ei, eflag, out_ei, 2 * E, N);
}

// Round 7
// 385.016 us; speedup vs baseline: 1.3293x; 1.3293x over previous
//
#include <hip/hip_runtime.h>

typedef unsigned short u16;
typedef __bf16 bf16x8 __attribute__((ext_vector_type(8)));
typedef float f32x4 __attribute__((ext_vector_type(4)));
typedef unsigned short u16x8 __attribute__((ext_vector_type(8)));

#define GA 256  // edge-chunk blocks for count/partition (must match in both passes)

static __device__ __forceinline__ float bf2f(u16 u) {
    return __uint_as_float(((unsigned)u) << 16);
}
static __device__ __forceinline__ u16 f2bf(float f) {
    unsigned u = __float_as_uint(f);
    unsigned r = (u + 0x7FFFu + ((u >> 16) & 1u)) >> 16;
    return (u16)r;
}

// ---- edge_index word-stride detection: int32-packed (1) vs int64-as-2-words (2)
__global__ void detect_kernel(const int* __restrict__ ei, int* __restrict__ flag) {
    if (blockIdx.x == 0 && threadIdx.x == 0) {
        int zc = 0;
        for (int t = 0; t < 64; ++t) zc += (ei[2 * t + 1] == 0) ? 1 : 0;
        *flag = (zc >= 60) ? 2 : 1;
    }
}
static __device__ __forceinline__ int ld_idx(const int* ei, int pos, int st, int N) {
    int v = ei[(size_t)pos * (size_t)st];
    return v < 0 ? 0 : (v >= N ? N - 1 : v);
}

// ================= generic exclusive scan over int array (length M) ==========
#define SCHUNK 4096
__global__ void xscan_reduce(const int* __restrict__ arr, int* __restrict__ bsum, int M) {
    __shared__ int sdata[256];
    int t = threadIdx.x;
    int base = blockIdx.x * SCHUNK + t * 16;
    int s = 0;
#pragma unroll
    for (int j = 0; j < 16; ++j) { int i = base + j; s += (i < M) ? arr[i] : 0; }
    sdata[t] = s;
    __syncthreads();
    for (int o = 128; o > 0; o >>= 1) {
        if (t < o) sdata[t] += sdata[t + o];
        __syncthreads();
    }
    if (t == 0) bsum[blockIdx.x] = sdata[0];
}
__global__ void scan_mid_kernel(int* __restrict__ bsum, int nb) {
    if (threadIdx.x == 0 && blockIdx.x == 0) {
        int run = 0;
        for (int b = 0; b < nb; ++b) { int v = bsum[b]; bsum[b] = run; run += v; }
    }
}
__global__ void xscan_final(int* __restrict__ arr, const int* __restrict__ bsum, int M) {
    __shared__ int sdata[256];
    int t = threadIdx.x;
    int base = blockIdx.x * SCHUNK + t * 16;
    int v[16];
    int s = 0;
#pragma unroll
    for (int j = 0; j < 16; ++j) {
        int i = base + j;
        v[j] = (i < M) ? arr[i] : 0;
        s += v[j];
    }
    sdata[t] = s;
    __syncthreads();
    for (int o = 1; o < 256; o <<= 1) {
        int add = (t >= o) ? sdata[t - o] : 0;
        __syncthreads();
        sdata[t] += add;
        __syncthreads();
    }
    int excl = (t == 0) ? 0 : sdata[t - 1];
    int off = bsum[blockIdx.x] + excl;
#pragma unroll
    for (int j = 0; j < 16; ++j) {
        int i = base + j;
        if (i < M) { arr[i] = off; off += v[j]; }
    }
}

// ================= radix partition by dst bucket (LDS cursors only) ==========
__global__ __launch_bounds__(256) void partition_kernel(const int* __restrict__ ei,
                                                        const int* __restrict__ flag,
                                                        const int* __restrict__ offs,
                                                        unsigned* __restrict__ ebuf, int E,
                                                        int N) {
    __shared__ int cur[1024];
    const int K = (N + 127) >> 7;
    const int bh = blockIdx.x;
    for (int k = threadIdx.x; k < K; k += 256) cur[k] = offs[(size_t)k * GA + bh];
    __syncthreads();
    const int st = *flag;
    const int chunk = (E + GA - 1) / GA;
    const int lo = bh * chunk;
    const int hi = (lo + chunk < E) ? lo + chunk : E;
    for (int j = lo + (int)threadIdx.x; j < hi; j += 256) {
        int d = ld_idx(ei, E + j, st, N);
        int s = ld_idx(ei, j, st, N);
        int pos = atomicAdd(&cur[d >> 7], 1);
        ebuf[pos] = ((unsigned)(d & 127) << 25) | (unsigned)s;
    }
}

// ================= per-bucket CSR build (LDS atomics only) ===================
__global__ __launch_bounds__(256) void csr_build(const unsigned* __restrict__ ebuf,
                                                 const int* __restrict__ offs,
                                                 int* __restrict__ rowptr,
                                                 int* __restrict__ col, int E, int N, int ET) {
    __shared__ int dg[128];
    __shared__ int sc[128];
    __shared__ int cur[128];
    const int K = (N + 127) >> 7;
    const int k = blockIdx.x;
    const int base = k << 7;
    const int nn = (N - base < 128) ? (N - base) : 128;
    const int e0 = offs[(size_t)k * GA];
    const int e1 = (k + 1 < K) ? offs[(size_t)(k + 1) * GA] : E;
    for (int t = threadIdx.x; t < 128; t += 256) dg[t] = 0;
    __syncthreads();
    for (int e = e0 + (int)threadIdx.x; e < e1; e += 256)
        atomicAdd(&dg[ebuf[e] >> 25], 1);
    __syncthreads();
    const int t = threadIdx.x;
    int v = 0;
    if (t < 128) {
        v = (t < nn) ? dg[t] + 1 : 0;  // +1 self loop
        sc[t] = v;
    }
    __syncthreads();
    for (int o = 1; o < 128; o <<= 1) {
        int add = 0;
        if (t < 128 && t >= o) add = sc[t - o];
        __syncthreads();
        if (t < 128) sc[t] += add;
        __syncthreads();
    }
    const int colbase = e0 + base;
    if (t < nn) {
        int rp = colbase + sc[t] - v;
        rowptr[base + t] = rp;
        col[rp] = base + t;  // self loop first
        cur[t] = rp + 1;
    }
    if (k == 0 && t == 0) rowptr[N] = ET;
    __syncthreads();
    for (int e = e0 + (int)threadIdx.x; e < e1; e += 256) {
        unsigned p = ebuf[e];
        int pos = atomicAdd(&cur[p >> 25], 1);
        col[pos] = (int)(p & 0x1FFFFFFu);
    }
}

// ---------------- fused GEMM: C[M,NC] = A[M,128] @ W[128,NC]
// W (f32, row-major [k][n]) is cooperatively staged to LDS TRANSPOSED as bf16
// wlds[n][k] (136-pad: 16B-aligned rows + bank spread). This replaces 256
// per-lane scalar VMEM loads per thread with 16 coalesced f32x4 loads + LDS,
// letting G1=1024 (4 blocks/CU = the VGPR-allowed occupancy) pay off.
template <int NC, bool AF32, int EPI, bool HIST>
__global__ __launch_bounds__(256) void gemm_fused(
    const void* __restrict__ Ap, const float* __restrict__ W, u16* __restrict__ Cout, int M,
    const float* __restrict__ av_s, const float* __restrict__ av_d, float* __restrict__ ssrc,
    float* __restrict__ sdst, const float* __restrict__ bl, float* __restrict__ outp,
    const int* __restrict__ ei, const int* __restrict__ flag, int* __restrict__ cntmat, int E,
    int ET, int N, int G1) {
    if (HIST && (int)blockIdx.x >= G1) {
        __shared__ int cnt[1024];
        const int bh = (int)blockIdx.x - G1;
        const int nga = (int)gridDim.x - G1;  // == GA
        const int K = (N + 127) >> 7;
        for (int k = threadIdx.x; k < K; k += 256) cnt[k] = 0;
        __syncthreads();
        const int st = *flag;
        const int chunk = (E + nga - 1) / nga;
        const int lo = bh * chunk;
        const int hi = (lo + chunk < E) ? lo + chunk : E;
        for (int j = lo + (int)threadIdx.x; j < hi; j += 256) {
            int d = ld_idx(ei, E + j, st, N);
            atomicAdd(&cnt[d >> 7], 1);
        }
        __syncthreads();
        for (int k = threadIdx.x; k < K; k += 256) cntmat[(size_t)k * nga + bh] = cnt[k];
        return;
    }
    const int lane = threadIdx.x & 63;
    const int quad = lane >> 4;
    const int r = lane & 15;
    const int gw = (blockIdx.x * 256 + threadIdx.x) >> 6;
    const int nw = G1 * 4;

    // ---- stage W^T into LDS (bf16), then load register fragments ----
    __shared__ u16 wlds[NC][136];
    {
        const int CH = NC / 4;  // f32x4 chunks per W row
        for (int idx = threadIdx.x; idx < 32 * NC; idx += 256) {
            int k = idx / CH;
            int n0 = (idx % CH) * 4;
            f32x4 v = *reinterpret_cast<const f32x4*>(W + (size_t)k * NC + n0);
#pragma unroll
            for (int j = 0; j < 4; ++j) wlds[n0 + j][k] = f2bf(v[j]);
        }
    }
    __syncthreads();
    bf16x8 bf[NC / 16][4];
#pragma unroll
    for (int nt = 0; nt < NC / 16; ++nt)
#pragma unroll
        for (int kk = 0; kk < 4; ++kk)
            bf[nt][kk] =
                *reinterpret_cast<const bf16x8*>(&wlds[nt * 16 + r][kk * 32 + quad * 8]);

    float avs[NC / 16], avd[NC / 16], blv[NC / 16];
    if (EPI == 1) {
#pragma unroll
        for (int nt = 0; nt < NC / 16; ++nt) {
            avs[nt] = av_s[nt * 16 + r];
            avd[nt] = av_d[nt * 16 + r];
        }
    }
    if (EPI == 2) {
#pragma unroll
        for (int nt = 0; nt < NC / 16; ++nt) blv[nt] = bl[nt * 16 + r];
    }

    const int ntiles = (M + 15) >> 4;
    for (int t = gw; t < ntiles; t += nw) {
        const int row0 = t << 4;
        bf16x8 af[4];
        if (AF32) {
            const float* arow = (const float*)Ap + (size_t)(row0 + r) * 128;
#pragma unroll
            for (int kk = 0; kk < 4; ++kk) {
                f32x4 f0 = *reinterpret_cast<const f32x4*>(arow + kk * 32 + quad * 8);
                f32x4 f1 = *reinterpret_cast<const f32x4*>(arow + kk * 32 + quad * 8 + 4);
                union { bf16x8 v; u16 s[8]; } u;
#pragma unroll
                for (int j = 0; j < 4; ++j) { u.s[j] = f2bf(f0[j]); u.s[4 + j] = f2bf(f1[j]); }
                af[kk] = u.v;
            }
        } else {
            const u16* arow = (const u16*)Ap + (size_t)(row0 + r) * 128;
#pragma unroll
            for (int kk = 0; kk < 4; ++kk)
                af[kk] = *reinterpret_cast<const bf16x8*>(arow + kk * 32 + quad * 8);
        }
        f32x4 acc[NC / 16];
#pragma unroll
        for (int nt = 0; nt < NC / 16; ++nt) acc[nt] = (f32x4){0.f, 0.f, 0.f, 0.f};
#pragma unroll
        for (int kk = 0; kk < 4; ++kk)
#pragma unroll
            for (int nt = 0; nt < NC / 16; ++nt)
                acc[nt] = __builtin_amdgcn_mfma_f32_16x16x32_bf16(af[kk], bf[nt][kk],
                                                                  acc[nt], 0, 0, 0);
        if (EPI != 2) {
#pragma unroll
            for (int nt = 0; nt < NC / 16; ++nt)
#pragma unroll
                for (int reg = 0; reg < 4; ++reg)
                    Cout[(size_t)(row0 + quad * 4 + reg) * NC + nt * 16 + r] =
                        f2bf(acc[nt][reg]);
        }
        if (EPI == 1) {
            float ps[4] = {0.f, 0.f, 0.f, 0.f}, pd[4] = {0.f, 0.f, 0.f, 0.f};
#pragma unroll
            for (int nt = 0; nt < NC / 16; ++nt)
#pragma unroll
                for (int reg = 0; reg < 4; ++reg) {
                    ps[reg] += acc[nt][reg] * avs[nt];
                    pd[reg] += acc[nt][reg] * avd[nt];
                }
#pragma unroll
            for (int o = 1; o < 16; o <<= 1)
#pragma unroll
                for (int reg = 0; reg < 4; ++reg) {
                    ps[reg] += __shfl_xor(ps[reg], o);
                    pd[reg] += __shfl_xor(pd[reg], o);
                }
            if (r == 0) {
#pragma unroll
                for (int reg = 0; reg < 4; ++reg) {
                    ssrc[row0 + quad * 4 + reg] = ps[reg];
                    sdst[row0 + quad * 4 + reg] = pd[reg];
                }
            }
        }
        if (EPI == 2) {
#pragma unroll
            for (int reg = 0; reg < 4; ++reg) {
                float v[NC / 16];
                float m = -3.4e38f;
#pragma unroll
                for (int nt = 0; nt < NC / 16; ++nt) {
                    v[nt] = acc[nt][reg] + blv[nt];
                    m = fmaxf(m, v[nt]);
                }
#pragma unroll
                for (int o = 1; o < 16; o <<= 1) m = fmaxf(m, __shfl_xor(m, o));
                float s = 0.f;
#pragma unroll
                for (int nt = 0; nt < NC / 16; ++nt) s += __expf(v[nt] - m);
#pragma unroll
                for (int o = 1; o < 16; o <<= 1) s += __shfl_xor(s, o);
                float L = __logf(s);
                const size_t rb = (size_t)(row0 + quad * 4 + reg) * NC;
#pragma unroll
                for (int nt = 0; nt < NC / 16; ++nt)
                    outp[rb + nt * 16 + r] = v[nt] - m - L;
            }
        }
    }
}

// ---------------- SINGLE-PASS agg over CSR: 16-lane group per dst node.
// Deferred softmax (acc and sm unnormalized, scale at end). 8-edge batched
// main loop; bf16-truncated weights packed via v_perm feed v_dot2_f32_bf16.
// MODE 1: out = relu(acc/sm + b).  MODE 2: out = acc/sm + b + skip.
template <int MODE>
__global__ __launch_bounds__(256) void agg_fused(
    const int* __restrict__ rowptr, const int* __restrict__ col,
    const float* __restrict__ ssrc, const float* __restrict__ sdst,
    const u16* __restrict__ h, const float* __restrict__ b, const u16* __restrict__ skip,
    u16* __restrict__ out, int N) {
    const int lane = threadIdx.x & 63;
    const int gwave = (blockIdx.x * 256 + threadIdx.x) >> 6;
    const int grp = lane >> 4;
    const int ln = lane & 15;
    const int i = gwave * 4 + grp;
    if (i >= N) return;
    const int start = rowptr[i], end = rowptr[i + 1];
    const float sd = sdst[i];
    const size_t coff = (size_t)ln * 8;

    float acc[8] = {0.f, 0.f, 0.f, 0.f, 0.f, 0.f, 0.f, 0.f};
    float sm = 0.f;
    int e = start;
    for (; e + 8 <= end; e += 8) {
        int c[8];
#pragma unroll
        for (int q = 0; q < 8; ++q) c[q] = col[e + q];
        float s[8];
#pragma unroll
        for (int q = 0; q < 8; ++q) s[q] = ssrc[c[q]];
        union { u16x8 v; unsigned w[4]; } r[8];
#pragma unroll
        for (int q = 0; q < 8; ++q)
            r[q].v = *reinterpret_cast<const u16x8*>(h + (size_t)c[q] * 128 + coff);
        unsigned uu[8];
#pragma unroll
        for (int q = 0; q < 8; ++q) {
            float sc = s[q] + sd;
            sc = sc > 0.f ? sc : 0.2f * sc;
            float w = __expf(fminf(sc, 60.f));
            uu[q] = __float_as_uint(w) & 0xFFFF0000u;
            sm += __uint_as_float(uu[q]);
        }
#pragma unroll
        for (int p = 0; p < 4; ++p) {
            unsigned wp = __builtin_amdgcn_perm(uu[2 * p + 1], uu[2 * p], 0x07060302u);
#pragma unroll
            for (int jw = 0; jw < 4; ++jw) {
                unsigned lo = __builtin_amdgcn_perm(r[2 * p + 1].w[jw], r[2 * p].w[jw],
                                                    0x05040100u);
                unsigned hi = __builtin_amdgcn_perm(r[2 * p + 1].w[jw], r[2 * p].w[jw],
                                                    0x07060302u);
                asm("v_dot2_f32_bf16 %0, %1, %2, %0" : "+v"(acc[2 * jw]) : "v"(lo), "v"(wp));
                asm("v_dot2_f32_bf16 %0, %1, %2, %0"
                    : "+v"(acc[2 * jw + 1])
                    : "v"(hi), "v"(wp));
            }
        }
    }
    if (e + 4 <= end) {
        int c0 = col[e], c1 = col[e + 1], c2 = col[e + 2], c3 = col[e + 3];
        float s0 = ssrc[c0] + sd;
        float s1 = ssrc[c1] + sd;
        float s2 = ssrc[c2] + sd;
        float s3 = ssrc[c3] + sd;
        union { u16x8 v; unsigned w[4]; } r0, r1, r2, r3;
        r0.v = *reinterpret_cast<const u16x8*>(h + (size_t)c0 * 128 + coff);
        r1.v = *reinterpret_cast<const u16x8*>(h + (size_t)c1 * 128 + coff);
        r2.v = *reinterpret_cast<const u16x8*>(h + (size_t)c2 * 128 + coff);
        r3.v = *reinterpret_cast<const u16x8*>(h + (size_t)c3 * 128 + coff);
        s0 = s0 > 0.f ? s0 : 0.2f * s0;
        s1 = s1 > 0.f ? s1 : 0.2f * s1;
        s2 = s2 > 0.f ? s2 : 0.2f * s2;
        s3 = s3 > 0.f ? s3 : 0.2f * s3;
        float w0 = __expf(fminf(s0, 60.f));
        float w1 = __expf(fminf(s1, 60.f));
        float w2 = __expf(fminf(s2, 60.f));
        float w3 = __expf(fminf(s3, 60.f));
        unsigned u0 = __float_as_uint(w0) & 0xFFFF0000u;
        unsigned u1 = __float_as_uint(w1) & 0xFFFF0000u;
        unsigned u2 = __float_as_uint(w2) & 0xFFFF0000u;
        unsigned u3 = __float_as_uint(w3) & 0xFFFF0000u;
        sm += (__uint_as_float(u0) + __uint_as_float(u1)) +
              (__uint_as_float(u2) + __uint_as_float(u3));
        unsigned wp01 = __builtin_amdgcn_perm(u1, u0, 0x07060302u);
        unsigned wp23 = __builtin_amdgcn_perm(u3, u2, 0x07060302u);
#pragma unroll
        for (int jw = 0; jw < 4; ++jw) {
            unsigned lo01 = __builtin_amdgcn_perm(r1.w[jw], r0.w[jw], 0x05040100u);
            unsigned hi01 = __builtin_amdgcn_perm(r1.w[jw], r0.w[jw], 0x07060302u);
            unsigned lo23 = __builtin_amdgcn_perm(r3.w[jw], r2.w[jw], 0x05040100u);
            unsigned hi23 = __builtin_amdgcn_perm(r3.w[jw], r2.w[jw], 0x07060302u);
            asm("v_dot2_f32_bf16 %0, %1, %2, %0" : "+v"(acc[2 * jw]) : "v"(lo01), "v"(wp01));
            asm("v_dot2_f32_bf16 %0, %1, %2, %0" : "+v"(acc[2 * jw + 1]) : "v"(hi01), "v"(wp01));
            asm("v_dot2_f32_bf16 %0, %1, %2, %0" : "+v"(acc[2 * jw]) : "v"(lo23), "v"(wp23));
            asm("v_dot2_f32_bf16 %0, %1, %2, %0" : "+v"(acc[2 * jw + 1]) : "v"(hi23), "v"(wp23));
        }
        e += 4;
    }
    if (e + 2 <= end) {
        int c0 = col[e], c1 = col[e + 1];
        float s0 = ssrc[c0] + sd;
        float s1 = ssrc[c1] + sd;
        union { u16x8 v; unsigned w[4]; } r0, r1;
        r0.v = *reinterpret_cast<const u16x8*>(h + (size_t)c0 * 128 + coff);
        r1.v = *reinterpret_cast<const u16x8*>(h + (size_t)c1 * 128 + coff);
        s0 = s0 > 0.f ? s0 : 0.2f * s0;
        s1 = s1 > 0.f ? s1 : 0.2f * s1;
        float w0 = __expf(fminf(s0, 60.f));
        float w1 = __expf(fminf(s1, 60.f));
        unsigned u0 = __float_as_uint(w0) & 0xFFFF0000u;
        unsigned u1 = __float_as_uint(w1) & 0xFFFF0000u;
        sm += __uint_as_float(u0) + __uint_as_float(u1);
        unsigned wp01 = __builtin_amdgcn_perm(u1, u0, 0x07060302u);
#pragma unroll
        for (int jw = 0; jw < 4; ++jw) {
            unsigned lo01 = __builtin_amdgcn_perm(r1.w[jw], r0.w[jw], 0x05040100u);
            unsigned hi01 = __builtin_amdgcn_perm(r1.w[jw], r0.w[jw], 0x07060302u);
            asm("v_dot2_f32_bf16 %0, %1, %2, %0" : "+v"(acc[2 * jw]) : "v"(lo01), "v"(wp01));
            asm("v_dot2_f32_bf16 %0, %1, %2, %0" : "+v"(acc[2 * jw + 1]) : "v"(hi01), "v"(wp01));
        }
        e += 2;
    }
    if (e < end) {
        int c0 = col[e];
        float s0 = ssrc[c0] + sd;
        s0 = s0 > 0.f ? s0 : 0.2f * s0;
        float w0 = __expf(fminf(s0, 60.f));
        unsigned u0 = __float_as_uint(w0) & 0xFFFF0000u;
        float wt = __uint_as_float(u0);
        sm += wt;
        const u16x8 r0 = *reinterpret_cast<const u16x8*>(h + (size_t)c0 * 128 + coff);
#pragma unroll
        for (int j = 0; j < 8; ++j) acc[j] += wt * bf2f(r0[j]);
    }
    const float rd = 1.f / sm;

    u16x8 o;
    if (MODE == 1) {
#pragma unroll
        for (int j = 0; j < 8; ++j) {
            float v = acc[j] * rd + b[coff + j];
            v = v > 0.f ? v : 0.f;
            o[j] = f2bf(v);
        }
    } else {
        const u16x8 sk = *reinterpret_cast<const u16x8*>(skip + (size_t)i * 128 + coff);
#pragma unroll
        for (int j = 0; j < 8; ++j) {
            float v = acc[j] * rd + b[coff + j] + bf2f(sk[j]);
            o[j] = f2bf(v);
        }
    }
    *reinterpret_cast<u16x8*>(out + (size_t)i * 128 + coff) = o;
}

// ---------------- echo edge_index as f32 (output 1)
__global__ void copy_ei_kernel(const int* __restrict__ ei, const int* __restrict__ flag,
                               float* __restrict__ out, int n, int N) {
    int j = blockIdx.x * 256 + threadIdx.x;
    if (j < n) out[j] = (float)ld_idx(ei, j, *flag, N);
}

extern "C" void kernel_launch(void* const* d_in, const int* in_sizes, int n_in, void* d_out,
                              int out_size, void* d_ws, size_t ws_size, hipStream_t stream) {
    int ix = 0, iei = 1;
    if (in_sizes[0] < in_sizes[1]) { ix = 1; iei = 0; }
    const float* x = (const float*)d_in[ix];
    const int* ei = (const int*)d_in[iei];
    const float* W1 = (const float*)d_in[2];
    const float* a1s = (const float*)d_in[3];
    const float* a1d = (const float*)d_in[4];
    const float* b1 = (const float*)d_in[5];
    const float* W2 = (const float*)d_in[6];
    const float* a2s = (const float*)d_in[7];
    const float* a2d = (const float*)d_in[8];
    const float* b2 = (const float*)d_in[9];
    const float* Wl = (const float*)d_in[10];
    const float* bl = (const float*)d_in[11];

    const int N = in_sizes[ix] / 128;
    const int E = (out_size - N * 64) / 2;  // out = [logp N*64 | edge_index 2E], f32
    const int ET = E + N;
    const int K = (N + 127) >> 7;   // dst buckets of 128 nodes
    const int Mscan = K * GA;       // cntmat elements

    char* ws = (char*)d_ws;
    size_t off = 0;
    auto alloc = [&](size_t bytes) {
        void* p = ws + off;
        off += (bytes + 255) & ~(size_t)255;
        return p;
    };
    u16* h = (u16*)alloc((size_t)N * 128 * 2);   // bf16 gemm out / gather source
    u16* h1 = (u16*)alloc((size_t)N * 128 * 2);  // bf16 layer-1 activation (skip input)
    u16* o2 = (u16*)alloc((size_t)N * 128 * 2);  // bf16 layer-2 out (final gemm input)
    float* ssrc = (float*)alloc((size_t)N * 4);
    float* sdst = (float*)alloc((size_t)N * 4);
    int* eflag = (int*)alloc(256);
    int* cntmat = (int*)alloc((size_t)Mscan * 4);  // per-(bucket,block) counts -> offsets
    int* rowptr = (int*)alloc((size_t)(N + 1) * 4);
    int* bsum = (int*)alloc(4096);
    int* colv = (int*)alloc((size_t)ET * 4);
    // ebuf (partitioned packed edges, E u32) aliases h1: last read in csr_build,
    // h1 first written by agg_fused<1> afterwards (stream-ordered).
    unsigned* ebuf = (unsigned*)h1;

    float* out_logp = (float*)d_out;
    float* out_ei = out_logp + (size_t)N * 64;

    dim3 blk(256);
    const int ngrid4 = (N + 15) / 16;  // 16-lane group per node, 16 nodes/block
    const int nbx = (Mscan + SCHUNK - 1) / SCHUNK;
    const int G1 = 1024;  // gemm blocks: 4 blocks/CU (= VGPR-allowed occupancy)

    detect_kernel<<<1, 64, 0, stream>>>(ei, eflag);

    // ---- layer-1 GEMM (+scores epilogue) fused with LDS bucket-count ----
    gemm_fused<128, true, 1, true><<<G1 + GA, blk, 0, stream>>>(
        x, W1, h, N, a1s, a1d, ssrc, sdst, nullptr, nullptr, ei, eflag, cntmat, E, ET, N, G1);

    // ---- exclusive scan of cntmat -> per-(bucket,block) offsets ----
    xscan_reduce<<<nbx, blk, 0, stream>>>(cntmat, bsum, Mscan);
    scan_mid_kernel<<<1, 64, 0, stream>>>(bsum, nbx);
    xscan_final<<<nbx, blk, 0, stream>>>(cntmat, bsum, Mscan);

    // ---- radix partition + per-bucket CSR build (LDS atomics only) ----
    partition_kernel<<<GA, blk, 0, stream>>>(ei, eflag, cntmat, ebuf, E, N);
    csr_build<<<K, blk, 0, stream>>>(ebuf, cntmat, rowptr, colv, E, N, ET);

    // ---- layer 1 aggregation (single-pass unnormalized + relu/bias) ----
    agg_fused<1><<<ngrid4, blk, 0, stream>>>(rowptr, colv, ssrc, sdst, h, b1, nullptr, h1, N);

    // ---- layer 2 ----
    gemm_fused<128, false, 1, false><<<G1, blk, 0, stream>>>(
        h1, W2, h, N, a2s, a2d, ssrc, sdst, nullptr, nullptr, nullptr, nullptr, nullptr, 0, 0,
        N, G1);
    agg_fused<2><<<ngrid4, blk, 0, stream>>>(rowptr, colv, ssrc, sdst, h, b2, h1, o2, N);

    // ---- final linear with fused log_softmax ----
    gemm_fused<64, false, 2, false><<<G1, blk, 0, stream>>>(
        o2, Wl, nullptr, N, nullptr, nullptr, nullptr, nullptr, bl, out_logp, nullptr, nullptr,
        nullptr, 0, 0, N, G1);

    copy_ei_kernel<<<(2 * E + 255) / 256, blk, 0, stream>>>(ei, eflag, out_ei, 2 * E, N);
}

// Round 8
// 379.259 us; speedup vs baseline: 1.3495x; 1.0152x over previous
//
#include <hip/hip_runtime.h>

typedef unsigned short u16;
typedef __bf16 bf16x8 __attribute__((ext_vector_type(8)));
typedef float f32x4 __attribute__((ext_vector_type(4)));
typedef unsigned short u16x8 __attribute__((ext_vector_type(8)));

#define GA 256  // edge-chunk blocks for count/partition (must match in both passes)

static __device__ __forceinline__ float bf2f(u16 u) {
    return __uint_as_float(((unsigned)u) << 16);
}
static __device__ __forceinline__ u16 f2bf(float f) {
    unsigned u = __float_as_uint(f);
    unsigned r = (u + 0x7FFFu + ((u >> 16) & 1u)) >> 16;
    return (u16)r;
}

// ---- edge_index word-stride detection: int32-packed (1) vs int64-as-2-words (2)
__global__ void detect_kernel(const int* __restrict__ ei, int* __restrict__ flag) {
    if (blockIdx.x == 0 && threadIdx.x == 0) {
        int zc = 0;
        for (int t = 0; t < 64; ++t) zc += (ei[2 * t + 1] == 0) ? 1 : 0;
        *flag = (zc >= 60) ? 2 : 1;
    }
}
static __device__ __forceinline__ int ld_idx(const int* ei, int pos, int st, int N) {
    int v = ei[(size_t)pos * (size_t)st];
    return v < 0 ? 0 : (v >= N ? N - 1 : v);
}

// ================= generic exclusive scan over int array (length M) ==========
#define SCHUNK 4096
__global__ void xscan_reduce(const int* __restrict__ arr, int* __restrict__ bsum, int M) {
    __shared__ int sdata[256];
    int t = threadIdx.x;
    int base = blockIdx.x * SCHUNK + t * 16;
    int s = 0;
#pragma unroll
    for (int j = 0; j < 16; ++j) { int i = base + j; s += (i < M) ? arr[i] : 0; }
    sdata[t] = s;
    __syncthreads();
    for (int o = 128; o > 0; o >>= 1) {
        if (t < o) sdata[t] += sdata[t + o];
        __syncthreads();
    }
    if (t == 0) bsum[blockIdx.x] = sdata[0];
}
__global__ void scan_mid_kernel(int* __restrict__ bsum, int nb) {
    if (threadIdx.x == 0 && blockIdx.x == 0) {
        int run = 0;
        for (int b = 0; b < nb; ++b) { int v = bsum[b]; bsum[b] = run; run += v; }
    }
}
__global__ void xscan_final(int* __restrict__ arr, const int* __restrict__ bsum, int M) {
    __shared__ int sdata[256];
    int t = threadIdx.x;
    int base = blockIdx.x * SCHUNK + t * 16;
    int v[16];
    int s = 0;
#pragma unroll
    for (int j = 0; j < 16; ++j) {
        int i = base + j;
        v[j] = (i < M) ? arr[i] : 0;
        s += v[j];
    }
    sdata[t] = s;
    __syncthreads();
    for (int o = 1; o < 256; o <<= 1) {
        int add = (t >= o) ? sdata[t - o] : 0;
        __syncthreads();
        sdata[t] += add;
        __syncthreads();
    }
    int excl = (t == 0) ? 0 : sdata[t - 1];
    int off = bsum[blockIdx.x] + excl;
#pragma unroll
    for (int j = 0; j < 16; ++j) {
        int i = base + j;
        if (i < M) { arr[i] = off; off += v[j]; }
    }
}

// ================= radix partition by dst bucket (LDS cursors only) ==========
__global__ __launch_bounds__(256) void partition_kernel(const int* __restrict__ ei,
                                                        const int* __restrict__ flag,
                                                        const int* __restrict__ offs,
                                                        unsigned* __restrict__ ebuf, int E,
                                                        int N) {
    __shared__ int cur[1024];
    const int K = (N + 127) >> 7;
    const int bh = blockIdx.x;
    for (int k = threadIdx.x; k < K; k += 256) cur[k] = offs[(size_t)k * GA + bh];
    __syncthreads();
    const int st = *flag;
    const int chunk = (E + GA - 1) / GA;
    const int lo = bh * chunk;
    const int hi = (lo + chunk < E) ? lo + chunk : E;
    for (int j = lo + (int)threadIdx.x; j < hi; j += 256) {
        int d = ld_idx(ei, E + j, st, N);
        int s = ld_idx(ei, j, st, N);
        int pos = atomicAdd(&cur[d >> 7], 1);
        ebuf[pos] = ((unsigned)(d & 127) << 25) | (unsigned)s;
    }
}

// ================= per-bucket CSR build (LDS atomics only) ===================
__global__ __launch_bounds__(256) void csr_build(const unsigned* __restrict__ ebuf,
                                                 const int* __restrict__ offs,
                                                 int* __restrict__ rowptr,
                                                 int* __restrict__ col, int E, int N, int ET) {
    __shared__ int dg[128];
    __shared__ int sc[128];
    __shared__ int cur[128];
    const int K = (N + 127) >> 7;
    const int k = blockIdx.x;
    const int base = k << 7;
    const int nn = (N - base < 128) ? (N - base) : 128;
    const int e0 = offs[(size_t)k * GA];
    const int e1 = (k + 1 < K) ? offs[(size_t)(k + 1) * GA] : E;
    for (int t = threadIdx.x; t < 128; t += 256) dg[t] = 0;
    __syncthreads();
    for (int e = e0 + (int)threadIdx.x; e < e1; e += 256)
        atomicAdd(&dg[ebuf[e] >> 25], 1);
    __syncthreads();
    const int t = threadIdx.x;
    int v = 0;
    if (t < 128) {
        v = (t < nn) ? dg[t] + 1 : 0;  // +1 self loop
        sc[t] = v;
    }
    __syncthreads();
    for (int o = 1; o < 128; o <<= 1) {
        int add = 0;
        if (t < 128 && t >= o) add = sc[t - o];
        __syncthreads();
        if (t < 128) sc[t] += add;
        __syncthreads();
    }
    const int colbase = e0 + base;
    if (t < nn) {
        int rp = colbase + sc[t] - v;
        rowptr[base + t] = rp;
        col[rp] = base + t;  // self loop first
        cur[t] = rp + 1;
    }
    if (k == 0 && t == 0) rowptr[N] = ET;
    __syncthreads();
    for (int e = e0 + (int)threadIdx.x; e < e1; e += 256) {
        unsigned p = ebuf[e];
        int pos = atomicAdd(&cur[p >> 25], 1);
        col[pos] = (int)(p & 0x1FFFFFFu);
    }
}

// ---------------- fused GEMM: C[M,NC] = A[M,128] @ W[128,NC]
// W (f32, row-major [k][n]) is cooperatively staged to LDS TRANSPOSED as bf16
// wlds[n][k] (+8 u16 pad: 16B-aligned rows, 2-way-free bank spread on the
// staging writes). Replaces the 256 per-lane scalar VMEM loads (+ ~1500 VALU
// f2bf ops) per thread of the register-preload with 16 coalesced f32x4 loads.
// G1 is per-launch: 512 for gemm1 (so 512+GA=768 blocks co-reside at 4
// blocks/CU and the fused hist runs CONCURRENT), 1024 for gemm2/3 (no hist ->
// 4 blocks/CU, double the resident waves of these latency-bound kernels).
template <int NC, bool AF32, int EPI, bool HIST>
__global__ __launch_bounds__(256) void gemm_fused(
    const void* __restrict__ Ap, const float* __restrict__ W, u16* __restrict__ Cout, int M,
    const float* __restrict__ av_s, const float* __restrict__ av_d, float* __restrict__ ssrc,
    float* __restrict__ sdst, const float* __restrict__ bl, float* __restrict__ outp,
    const int* __restrict__ ei, const int* __restrict__ flag, int* __restrict__ cntmat, int E,
    int ET, int N, int G1) {
    if (HIST && (int)blockIdx.x >= G1) {
        __shared__ int cnt[1024];
        const int bh = (int)blockIdx.x - G1;
        const int nga = (int)gridDim.x - G1;  // == GA
        const int K = (N + 127) >> 7;
        for (int k = threadIdx.x; k < K; k += 256) cnt[k] = 0;
        __syncthreads();
        const int st = *flag;
        const int chunk = (E + nga - 1) / nga;
        const int lo = bh * chunk;
        const int hi = (lo + chunk < E) ? lo + chunk : E;
        for (int j = lo + (int)threadIdx.x; j < hi; j += 256) {
            int d = ld_idx(ei, E + j, st, N);
            atomicAdd(&cnt[d >> 7], 1);
        }
        __syncthreads();
        for (int k = threadIdx.x; k < K; k += 256) cntmat[(size_t)k * nga + bh] = cnt[k];
        return;
    }
    const int lane = threadIdx.x & 63;
    const int quad = lane >> 4;
    const int r = lane & 15;
    const int gw = (blockIdx.x * 256 + threadIdx.x) >> 6;
    const int nw = G1 * 4;

    // ---- stage W^T into LDS (bf16), then load register fragments ----
    __shared__ u16 wlds[NC][136];
    {
        const int CH = NC / 4;  // f32x4 chunks per W row
        for (int idx = threadIdx.x; idx < 32 * NC; idx += 256) {
            int k = idx / CH;
            int n0 = (idx % CH) * 4;
            f32x4 v = *reinterpret_cast<const f32x4*>(W + (size_t)k * NC + n0);
#pragma unroll
            for (int j = 0; j < 4; ++j) wlds[n0 + j][k] = f2bf(v[j]);
        }
    }
    __syncthreads();
    bf16x8 bf[NC / 16][4];
#pragma unroll
    for (int nt = 0; nt < NC / 16; ++nt)
#pragma unroll
        for (int kk = 0; kk < 4; ++kk)
            bf[nt][kk] =
                *reinterpret_cast<const bf16x8*>(&wlds[nt * 16 + r][kk * 32 + quad * 8]);

    float avs[NC / 16], avd[NC / 16], blv[NC / 16];
    if (EPI == 1) {
#pragma unroll
        for (int nt = 0; nt < NC / 16; ++nt) {
            avs[nt] = av_s[nt * 16 + r];
            avd[nt] = av_d[nt * 16 + r];
        }
    }
    if (EPI == 2) {
#pragma unroll
        for (int nt = 0; nt < NC / 16; ++nt) blv[nt] = bl[nt * 16 + r];
    }

    const int ntiles = (M + 15) >> 4;
    for (int t = gw; t < ntiles; t += nw) {
        const int row0 = t << 4;
        bf16x8 af[4];
        if (AF32) {
            const float* arow = (const float*)Ap + (size_t)(row0 + r) * 128;
#pragma unroll
            for (int kk = 0; kk < 4; ++kk) {
                f32x4 f0 = *reinterpret_cast<const f32x4*>(arow + kk * 32 + quad * 8);
                f32x4 f1 = *reinterpret_cast<const f32x4*>(arow + kk * 32 + quad * 8 + 4);
                union { bf16x8 v; u16 s[8]; } u;
#pragma unroll
                for (int j = 0; j < 4; ++j) { u.s[j] = f2bf(f0[j]); u.s[4 + j] = f2bf(f1[j]); }
                af[kk] = u.v;
            }
        } else {
            const u16* arow = (const u16*)Ap + (size_t)(row0 + r) * 128;
#pragma unroll
            for (int kk = 0; kk < 4; ++kk)
                af[kk] = *reinterpret_cast<const bf16x8*>(arow + kk * 32 + quad * 8);
        }
        f32x4 acc[NC / 16];
#pragma unroll
        for (int nt = 0; nt < NC / 16; ++nt) acc[nt] = (f32x4){0.f, 0.f, 0.f, 0.f};
#pragma unroll
        for (int kk = 0; kk < 4; ++kk)
#pragma unroll
            for (int nt = 0; nt < NC / 16; ++nt)
                acc[nt] = __builtin_amdgcn_mfma_f32_16x16x32_bf16(af[kk], bf[nt][kk],
                                                                  acc[nt], 0, 0, 0);
        if (EPI != 2) {
#pragma unroll
            for (int nt = 0; nt < NC / 16; ++nt)
#pragma unroll
                for (int reg = 0; reg < 4; ++reg)
                    Cout[(size_t)(row0 + quad * 4 + reg) * NC + nt * 16 + r] =
                        f2bf(acc[nt][reg]);
        }
        if (EPI == 1) {
            float ps[4] = {0.f, 0.f, 0.f, 0.f}, pd[4] = {0.f, 0.f, 0.f, 0.f};
#pragma unroll
            for (int nt = 0; nt < NC / 16; ++nt)
#pragma unroll
                for (int reg = 0; reg < 4; ++reg) {
                    ps[reg] += acc[nt][reg] * avs[nt];
                    pd[reg] += acc[nt][reg] * avd[nt];
                }
#pragma unroll
            for (int o = 1; o < 16; o <<= 1)
#pragma unroll
                for (int reg = 0; reg < 4; ++reg) {
                    ps[reg] += __shfl_xor(ps[reg], o);
                    pd[reg] += __shfl_xor(pd[reg], o);
                }
            if (r == 0) {
#pragma unroll
                for (int reg = 0; reg < 4; ++reg) {
                    ssrc[row0 + quad * 4 + reg] = ps[reg];
                    sdst[row0 + quad * 4 + reg] = pd[reg];
                }
            }
        }
        if (EPI == 2) {
#pragma unroll
            for (int reg = 0; reg < 4; ++reg) {
                float v[NC / 16];
                float m = -3.4e38f;
#pragma unroll
                for (int nt = 0; nt < NC / 16; ++nt) {
                    v[nt] = acc[nt][reg] + blv[nt];
                    m = fmaxf(m, v[nt]);
                }
#pragma unroll
                for (int o = 1; o < 16; o <<= 1) m = fmaxf(m, __shfl_xor(m, o));
                float s = 0.f;
#pragma unroll
                for (int nt = 0; nt < NC / 16; ++nt) s += __expf(v[nt] - m);
#pragma unroll
                for (int o = 1; o < 16; o <<= 1) s += __shfl_xor(s, o);
                float L = __logf(s);
                const size_t rb = (size_t)(row0 + quad * 4 + reg) * NC;
#pragma unroll
                for (int nt = 0; nt < NC / 16; ++nt)
                    outp[rb + nt * 16 + r] = v[nt] - m - L;
            }
        }
    }
}

// ---------------- SINGLE-PASS agg over CSR: 16-lane group per dst node.
// Deferred softmax (acc and sm unnormalized, scale at end). 8-edge batched
// main loop; bf16-truncated weights packed via v_perm feed v_dot2_f32_bf16.
// MODE 1: out = relu(acc/sm + b).  MODE 2: out = acc/sm + b + skip.
template <int MODE>
__global__ __launch_bounds__(256) void agg_fused(
    const int* __restrict__ rowptr, const int* __restrict__ col,
    const float* __restrict__ ssrc, const float* __restrict__ sdst,
    const u16* __restrict__ h, const float* __restrict__ b, const u16* __restrict__ skip,
    u16* __restrict__ out, int N) {
    const int lane = threadIdx.x & 63;
    const int gwave = (blockIdx.x * 256 + threadIdx.x) >> 6;
    const int grp = lane >> 4;
    const int ln = lane & 15;
    const int i = gwave * 4 + grp;
    if (i >= N) return;
    const int start = rowptr[i], end = rowptr[i + 1];
    const float sd = sdst[i];
    const size_t coff = (size_t)ln * 8;

    float acc[8] = {0.f, 0.f, 0.f, 0.f, 0.f, 0.f, 0.f, 0.f};
    float sm = 0.f;
    int e = start;
    for (; e + 8 <= end; e += 8) {
        int c[8];
#pragma unroll
        for (int q = 0; q < 8; ++q) c[q] = col[e + q];
        float s[8];
#pragma unroll
        for (int q = 0; q < 8; ++q) s[q] = ssrc[c[q]];
        union { u16x8 v; unsigned w[4]; } r[8];
#pragma unroll
        for (int q = 0; q < 8; ++q)
            r[q].v = *reinterpret_cast<const u16x8*>(h + (size_t)c[q] * 128 + coff);
        unsigned uu[8];
#pragma unroll
        for (int q = 0; q < 8; ++q) {
            float sc = s[q] + sd;
            sc = sc > 0.f ? sc : 0.2f * sc;
            float w = __expf(fminf(sc, 60.f));
            uu[q] = __float_as_uint(w) & 0xFFFF0000u;
            sm += __uint_as_float(uu[q]);
        }
#pragma unroll
        for (int p = 0; p < 4; ++p) {
            unsigned wp = __builtin_amdgcn_perm(uu[2 * p + 1], uu[2 * p], 0x07060302u);
#pragma unroll
            for (int jw = 0; jw < 4; ++jw) {
                unsigned lo = __builtin_amdgcn_perm(r[2 * p + 1].w[jw], r[2 * p].w[jw],
                                                    0x05040100u);
                unsigned hi = __builtin_amdgcn_perm(r[2 * p + 1].w[jw], r[2 * p].w[jw],
                                                    0x07060302u);
                asm("v_dot2_f32_bf16 %0, %1, %2, %0" : "+v"(acc[2 * jw]) : "v"(lo), "v"(wp));
                asm("v_dot2_f32_bf16 %0, %1, %2, %0"
                    : "+v"(acc[2 * jw + 1])
                    : "v"(hi), "v"(wp));
            }
        }
    }
    if (e + 4 <= end) {
        int c0 = col[e], c1 = col[e + 1], c2 = col[e + 2], c3 = col[e + 3];
        float s0 = ssrc[c0] + sd;
        float s1 = ssrc[c1] + sd;
        float s2 = ssrc[c2] + sd;
        float s3 = ssrc[c3] + sd;
        union { u16x8 v; unsigned w[4]; } r0, r1, r2, r3;
        r0.v = *reinterpret_cast<const u16x8*>(h + (size_t)c0 * 128 + coff);
        r1.v = *reinterpret_cast<const u16x8*>(h + (size_t)c1 * 128 + coff);
        r2.v = *reinterpret_cast<const u16x8*>(h + (size_t)c2 * 128 + coff);
        r3.v = *reinterpret_cast<const u16x8*>(h + (size_t)c3 * 128 + coff);
        s0 = s0 > 0.f ? s0 : 0.2f * s0;
        s1 = s1 > 0.f ? s1 : 0.2f * s1;
        s2 = s2 > 0.f ? s2 : 0.2f * s2;
        s3 = s3 > 0.f ? s3 : 0.2f * s3;
        float w0 = __expf(fminf(s0, 60.f));
        float w1 = __expf(fminf(s1, 60.f));
        float w2 = __expf(fminf(s2, 60.f));
        float w3 = __expf(fminf(s3, 60.f));
        unsigned u0 = __float_as_uint(w0) & 0xFFFF0000u;
        unsigned u1 = __float_as_uint(w1) & 0xFFFF0000u;
        unsigned u2 = __float_as_uint(w2) & 0xFFFF0000u;
        unsigned u3 = __float_as_uint(w3) & 0xFFFF0000u;
        sm += (__uint_as_float(u0) + __uint_as_float(u1)) +
              (__uint_as_float(u2) + __uint_as_float(u3));
        unsigned wp01 = __builtin_amdgcn_perm(u1, u0, 0x07060302u);
        unsigned wp23 = __builtin_amdgcn_perm(u3, u2, 0x07060302u);
#pragma unroll
        for (int jw = 0; jw < 4; ++jw) {
            unsigned lo01 = __builtin_amdgcn_perm(r1.w[jw], r0.w[jw], 0x05040100u);
            unsigned hi01 = __builtin_amdgcn_perm(r1.w[jw], r0.w[jw], 0x07060302u);
            unsigned lo23 = __builtin_amdgcn_perm(r3.w[jw], r2.w[jw], 0x05040100u);
            unsigned hi23 = __builtin_amdgcn_perm(r3.w[jw], r2.w[jw], 0x07060302u);
            asm("v_dot2_f32_bf16 %0, %1, %2, %0" : "+v"(acc[2 * jw]) : "v"(lo01), "v"(wp01));
            asm("v_dot2_f32_bf16 %0, %1, %2, %0" : "+v"(acc[2 * jw + 1]) : "v"(hi01), "v"(wp01));
            asm("v_dot2_f32_bf16 %0, %1, %2, %0" : "+v"(acc[2 * jw]) : "v"(lo23), "v"(wp23));
            asm("v_dot2_f32_bf16 %0, %1, %2, %0" : "+v"(acc[2 * jw + 1]) : "v"(hi23), "v"(wp23));
        }
        e += 4;
    }
    if (e + 2 <= end) {
        int c0 = col[e], c1 = col[e + 1];
        float s0 = ssrc[c0] + sd;
        float s1 = ssrc[c1] + sd;
        union { u16x8 v; unsigned w[4]; } r0, r1;
        r0.v = *reinterpret_cast<const u16x8*>(h + (size_t)c0 * 128 + coff);
        r1.v = *reinterpret_cast<const u16x8*>(h + (size_t)c1 * 128 + coff);
        s0 = s0 > 0.f ? s0 : 0.2f * s0;
        s1 = s1 > 0.f ? s1 : 0.2f * s1;
        float w0 = __expf(fminf(s0, 60.f));
        float w1 = __expf(fminf(s1, 60.f));
        unsigned u0 = __float_as_uint(w0) & 0xFFFF0000u;
        unsigned u1 = __float_as_uint(w1) & 0xFFFF0000u;
        sm += __uint_as_float(u0) + __uint_as_float(u1);
        unsigned wp01 = __builtin_amdgcn_perm(u1, u0, 0x07060302u);
#pragma unroll
        for (int jw = 0; jw < 4; ++jw) {
            unsigned lo01 = __builtin_amdgcn_perm(r1.w[jw], r0.w[jw], 0x05040100u);
            unsigned hi01 = __builtin_amdgcn_perm(r1.w[jw], r0.w[jw], 0x07060302u);
            asm("v_dot2_f32_bf16 %0, %1, %2, %0" : "+v"(acc[2 * jw]) : "v"(lo01), "v"(wp01));
            asm("v_dot2_f32_bf16 %0, %1, %2, %0" : "+v"(acc[2 * jw + 1]) : "v"(hi01), "v"(wp01));
        }
        e += 2;
    }
    if (e < end) {
        int c0 = col[e];
        float s0 = ssrc[c0] + sd;
        s0 = s0 > 0.f ? s0 : 0.2f * s0;
        float w0 = __expf(fminf(s0, 60.f));
        unsigned u0 = __float_as_uint(w0) & 0xFFFF0000u;
        float wt = __uint_as_float(u0);
        sm += wt;
        const u16x8 r0 = *reinterpret_cast<const u16x8*>(h + (size_t)c0 * 128 + coff);
#pragma unroll
        for (int j = 0; j < 8; ++j) acc[j] += wt * bf2f(r0[j]);
    }
    const float rd = 1.f / sm;

    u16x8 o;
    if (MODE == 1) {
#pragma unroll
        for (int j = 0; j < 8; ++j) {
            float v = acc[j] * rd + b[coff + j];
            v = v > 0.f ? v : 0.f;
            o[j] = f2bf(v);
        }
    } else {
        const u16x8 sk = *reinterpret_cast<const u16x8*>(skip + (size_t)i * 128 + coff);
#pragma unroll
        for (int j = 0; j < 8; ++j) {
            float v = acc[j] * rd + b[coff + j] + bf2f(sk[j]);
            o[j] = f2bf(v);
        }
    }
    *reinterpret_cast<u16x8*>(out + (size_t)i * 128 + coff) = o;
}

// ---------------- echo edge_index as f32 (output 1)
__global__ void copy_ei_kernel(const int* __restrict__ ei, const int* __restrict__ flag,
                               float* __restrict__ out, int n, int N) {
    int j = blockIdx.x * 256 + threadIdx.x;
    if (j < n) out[j] = (float)ld_idx(ei, j, *flag, N);
}

extern "C" void kernel_launch(void* const* d_in, const int* in_sizes, int n_in, void* d_out,
                              int out_size, void* d_ws, size_t ws_size, hipStream_t stream) {
    int ix = 0, iei = 1;
    if (in_sizes[0] < in_sizes[1]) { ix = 1; iei = 0; }
    const float* x = (const float*)d_in[ix];
    const int* ei = (const int*)d_in[iei];
    const float* W1 = (const float*)d_in[2];
    const float* a1s = (const float*)d_in[3];
    const float* a1d = (const float*)d_in[4];
    const float* b1 = (const float*)d_in[5];
    const float* W2 = (const float*)d_in[6];
    const float* a2s = (const float*)d_in[7];
    const float* a2d = (const float*)d_in[8];
    const float* b2 = (const float*)d_in[9];
    const float* Wl = (const float*)d_in[10];
    const float* bl = (const float*)d_in[11];

    const int N = in_sizes[ix] / 128;
    const int E = (out_size - N * 64) / 2;  // out = [logp N*64 | edge_index 2E], f32
    const int ET = E + N;
    const int K = (N + 127) >> 7;   // dst buckets of 128 nodes
    const int Mscan = K * GA;       // cntmat elements

    char* ws = (char*)d_ws;
    size_t off = 0;
    auto alloc = [&](size_t bytes) {
        void* p = ws + off;
        off += (bytes + 255) & ~(size_t)255;
        return p;
    };
    u16* h = (u16*)alloc((size_t)N * 128 * 2);   // bf16 gemm out / gather source
    u16* h1 = (u16*)alloc((size_t)N * 128 * 2);  // bf16 layer-1 activation (skip input)
    u16* o2 = (u16*)alloc((size_t)N * 128 * 2);  // bf16 layer-2 out (final gemm input)
    float* ssrc = (float*)alloc((size_t)N * 4);
    float* sdst = (float*)alloc((size_t)N * 4);
    int* eflag = (int*)alloc(256);
    int* cntmat = (int*)alloc((size_t)Mscan * 4);  // per-(bucket,block) counts -> offsets
    int* rowptr = (int*)alloc((size_t)(N + 1) * 4);
    int* bsum = (int*)alloc(4096);
    int* colv = (int*)alloc((size_t)ET * 4);
    // ebuf (partitioned packed edges, E u32) aliases h1: last read in csr_build,
    // h1 first written by agg_fused<1> afterwards (stream-ordered).
    unsigned* ebuf = (unsigned*)h1;

    float* out_logp = (float*)d_out;
    float* out_ei = out_logp + (size_t)N * 64;

    dim3 blk(256);
    const int ngrid4 = (N + 15) / 16;  // 16-lane group per node, 16 nodes/block
    const int nbx = (Mscan + SCHUNK - 1) / SCHUNK;
    const int G1a = 512;   // gemm1: 512+GA=768 blocks co-resident -> hist concurrent
    const int G1b = 1024;  // gemm2/3: 4 blocks/CU, no hist

    detect_kernel<<<1, 64, 0, stream>>>(ei, eflag);

    // ---- layer-1 GEMM (+scores epilogue) fused with LDS bucket-count ----
    gemm_fused<128, true, 1, true><<<G1a + GA, blk, 0, stream>>>(
        x, W1, h, N, a1s, a1d, ssrc, sdst, nullptr, nullptr, ei, eflag, cntmat, E, ET, N, G1a);

    // ---- exclusive scan of cntmat -> per-(bucket,block) offsets ----
    xscan_reduce<<<nbx, blk, 0, stream>>>(cntmat, bsum, Mscan);
    scan_mid_kernel<<<1, 64, 0, stream>>>(bsum, nbx);
    xscan_final<<<nbx, blk, 0, stream>>>(cntmat, bsum, Mscan);

    // ---- radix partition + per-bucket CSR build (LDS atomics only) ----
    partition_kernel<<<GA, blk, 0, stream>>>(ei, eflag, cntmat, ebuf, E, N);
    csr_build<<<K, blk, 0, stream>>>(ebuf, cntmat, rowptr, colv, E, N, ET);

    // ---- layer 1 aggregation (single-pass unnormalized + relu/bias) ----
    agg_fused<1><<<ngrid4, blk, 0, stream>>>(rowptr, colv, ssrc, sdst, h, b1, nullptr, h1, N);

    // ---- layer 2 ----
    gemm_fused<128, false, 1, false><<<G1b, blk, 0, stream>>>(
        h1, W2, h, N, a2s, a2d, ssrc, sdst, nullptr, nullptr, nullptr, nullptr, nullptr, 0, 0,
        N, G1b);
    agg_fused<2><<<ngrid4, blk, 0, stream>>>(rowptr, colv, ssrc, sdst, h, b2, h1, o2, N);

    // ---- final linear with fused log_softmax ----
    gemm_fused<64, false, 2, false><<<G1b, blk, 0, stream>>>(
        o2, Wl, nullptr, N, nullptr, nullptr, nullptr, nullptr, bl, out_logp, nullptr, nullptr,
        nullptr, 0, 0, N, G1b);

    copy_ei_kernel<<<(2 * E + 255) / 256, blk, 0, stream>>>(ei, eflag, out_ei, 2 * E, N);
}

// Round 9
// 357.709 us; speedup vs baseline: 1.4308x; 1.0602x over previous
//
#include <hip/hip_runtime.h>

typedef unsigned short u16;
typedef __bf16 bf16x8 __attribute__((ext_vector_type(8)));
typedef float f32x4 __attribute__((ext_vector_type(4)));
typedef unsigned short u16x8 __attribute__((ext_vector_type(8)));

#define GA 256  // edge-chunk blocks for count/partition (must match in both passes)
#define GC 256  // copy_ei blocks fused into gemm1 grid

static __device__ __forceinline__ float bf2f(u16 u) {
    return __uint_as_float(((unsigned)u) << 16);
}
static __device__ __forceinline__ u16 f2bf(float f) {
    unsigned u = __float_as_uint(f);
    unsigned r = (u + 0x7FFFu + ((u >> 16) & 1u)) >> 16;
    return (u16)r;
}

// ---- edge_index word-stride detection: int32-packed (1) vs int64-as-2-words (2)
__global__ void detect_kernel(const int* __restrict__ ei, int* __restrict__ flag) {
    if (blockIdx.x == 0 && threadIdx.x == 0) {
        int zc = 0;
        for (int t = 0; t < 64; ++t) zc += (ei[2 * t + 1] == 0) ? 1 : 0;
        *flag = (zc >= 60) ? 2 : 1;
    }
}
static __device__ __forceinline__ int ld_idx(const int* ei, int pos, int st, int N) {
    int v = ei[(size_t)pos * (size_t)st];
    return v < 0 ? 0 : (v >= N ? N - 1 : v);
}

// ================= generic exclusive scan over int array (length M) ==========
#define SCHUNK 4096
__global__ void xscan_reduce(const int* __restrict__ arr, int* __restrict__ bsum, int M) {
    __shared__ int sdata[256];
    int t = threadIdx.x;
    int base = blockIdx.x * SCHUNK + t * 16;
    int s = 0;
#pragma unroll
    for (int j = 0; j < 16; ++j) { int i = base + j; s += (i < M) ? arr[i] : 0; }
    sdata[t] = s;
    __syncthreads();
    for (int o = 128; o > 0; o >>= 1) {
        if (t < o) sdata[t] += sdata[t + o];
        __syncthreads();
    }
    if (t == 0) bsum[blockIdx.x] = sdata[0];
}
__global__ void scan_mid_kernel(int* __restrict__ bsum, int nb) {
    if (threadIdx.x == 0 && blockIdx.x == 0) {
        int run = 0;
        for (int b = 0; b < nb; ++b) { int v = bsum[b]; bsum[b] = run; run += v; }
    }
}
__global__ void xscan_final(int* __restrict__ arr, const int* __restrict__ bsum, int M) {
    __shared__ int sdata[256];
    int t = threadIdx.x;
    int base = blockIdx.x * SCHUNK + t * 16;
    int v[16];
    int s = 0;
#pragma unroll
    for (int j = 0; j < 16; ++j) {
        int i = base + j;
        v[j] = (i < M) ? arr[i] : 0;
        s += v[j];
    }
    sdata[t] = s;
    __syncthreads();
    for (int o = 1; o < 256; o <<= 1) {
        int add = (t >= o) ? sdata[t - o] : 0;
        __syncthreads();
        sdata[t] += add;
        __syncthreads();
    }
    int excl = (t == 0) ? 0 : sdata[t - 1];
    int off = bsum[blockIdx.x] + excl;
#pragma unroll
    for (int j = 0; j < 16; ++j) {
        int i = base + j;
        if (i < M) { arr[i] = off; off += v[j]; }
    }
}

// ================= radix partition by dst bucket (LDS cursors only) ==========
__global__ __launch_bounds__(256) void partition_kernel(const int* __restrict__ ei,
                                                        const int* __restrict__ flag,
                                                        const int* __restrict__ offs,
                                                        unsigned* __restrict__ ebuf, int E,
                                                        int N) {
    __shared__ int cur[1024];
    const int K = (N + 127) >> 7;
    const int bh = blockIdx.x;
    for (int k = threadIdx.x; k < K; k += 256) cur[k] = offs[(size_t)k * GA + bh];
    __syncthreads();
    const int st = *flag;
    const int chunk = (E + GA - 1) / GA;
    const int lo = bh * chunk;
    const int hi = (lo + chunk < E) ? lo + chunk : E;
    for (int j = lo + (int)threadIdx.x; j < hi; j += 256) {
        int d = ld_idx(ei, E + j, st, N);
        int s = ld_idx(ei, j, st, N);
        int pos = atomicAdd(&cur[d >> 7], 1);
        ebuf[pos] = ((unsigned)(d & 127) << 25) | (unsigned)s;
    }
}

// ================= per-bucket CSR build (LDS atomics only) ===================
__global__ __launch_bounds__(256) void csr_build(const unsigned* __restrict__ ebuf,
                                                 const int* __restrict__ offs,
                                                 int* __restrict__ rowptr,
                                                 int* __restrict__ col, int E, int N, int ET) {
    __shared__ int dg[128];
    __shared__ int sc[128];
    __shared__ int cur[128];
    const int K = (N + 127) >> 7;
    const int k = blockIdx.x;
    const int base = k << 7;
    const int nn = (N - base < 128) ? (N - base) : 128;
    const int e0 = offs[(size_t)k * GA];
    const int e1 = (k + 1 < K) ? offs[(size_t)(k + 1) * GA] : E;
    for (int t = threadIdx.x; t < 128; t += 256) dg[t] = 0;
    __syncthreads();
    for (int e = e0 + (int)threadIdx.x; e < e1; e += 256)
        atomicAdd(&dg[ebuf[e] >> 25], 1);
    __syncthreads();
    const int t = threadIdx.x;
    int v = 0;
    if (t < 128) {
        v = (t < nn) ? dg[t] + 1 : 0;  // +1 self loop
        sc[t] = v;
    }
    __syncthreads();
    for (int o = 1; o < 128; o <<= 1) {
        int add = 0;
        if (t < 128 && t >= o) add = sc[t - o];
        __syncthreads();
        if (t < 128) sc[t] += add;
        __syncthreads();
    }
    const int colbase = e0 + base;
    if (t < nn) {
        int rp = colbase + sc[t] - v;
        rowptr[base + t] = rp;
        col[rp] = base + t;  // self loop first
        cur[t] = rp + 1;
    }
    if (k == 0 && t == 0) rowptr[N] = ET;
    __syncthreads();
    for (int e = e0 + (int)threadIdx.x; e < e1; e += 256) {
        unsigned p = ebuf[e];
        int pos = atomicAdd(&cur[p >> 25], 1);
        col[pos] = (int)(p & 0x1FFFFFFu);
    }
}

// ---------------- fused GEMM: C[M,NC] = A[M,128] @ W[128,NC]
// MFMA 16x16x32 bf16, register-resident W frags (R5 form -- measured faster
// than LDS staging at G1=512 with full wave-level overlap).
// HIST grid layout (gemm1 only): [0,G1) gemm | [G1,G1+GA) LDS bucket-count |
// [G1+GA,G1+GA+GC) edge_index echo. 512+256+256 = 1024 blocks = exactly
// 4 blocks/CU at VGPR=120 -> all three classes co-resident, hist+copy overlap
// the latency-bound GEMM instead of running as serial kernels.
template <int NC, bool AF32, int EPI, bool HIST>
__global__ __launch_bounds__(256) void gemm_fused(
    const void* __restrict__ Ap, const float* __restrict__ W, u16* __restrict__ Cout, int M,
    const float* __restrict__ av_s, const float* __restrict__ av_d, float* __restrict__ ssrc,
    float* __restrict__ sdst, const float* __restrict__ bl, float* __restrict__ outp,
    const int* __restrict__ ei, const int* __restrict__ flag, int* __restrict__ cntmat,
    float* __restrict__ out_ei, int twoE, int E, int ET, int N, int G1) {
    if (HIST && (int)blockIdx.x >= G1 + GA) {  // ---- fused edge_index echo ----
        int tid = ((int)blockIdx.x - G1 - GA) * 256 + threadIdx.x;
        int stride = GC * 256;
        int st = *flag;
        for (int j = tid; j < twoE; j += stride) out_ei[j] = (float)ld_idx(ei, j, st, N);
        return;
    }
    if (HIST && (int)blockIdx.x >= G1) {  // ---- fused LDS bucket-count ----
        __shared__ int cnt[1024];
        const int bh = (int)blockIdx.x - G1;
        const int K = (N + 127) >> 7;
        for (int k = threadIdx.x; k < K; k += 256) cnt[k] = 0;
        __syncthreads();
        const int st = *flag;
        const int chunk = (E + GA - 1) / GA;
        const int lo = bh * chunk;
        const int hi = (lo + chunk < E) ? lo + chunk : E;
        for (int j = lo + (int)threadIdx.x; j < hi; j += 256) {
            int d = ld_idx(ei, E + j, st, N);
            atomicAdd(&cnt[d >> 7], 1);
        }
        __syncthreads();
        for (int k = threadIdx.x; k < K; k += 256) cntmat[(size_t)k * GA + bh] = cnt[k];
        return;
    }
    const int lane = threadIdx.x & 63;
    const int quad = lane >> 4;
    const int r = lane & 15;
    const int gw = (blockIdx.x * 256 + threadIdx.x) >> 6;
    const int nw = G1 * 4;

    bf16x8 bf[NC / 16][4];
#pragma unroll
    for (int nt = 0; nt < NC / 16; ++nt)
#pragma unroll
        for (int kk = 0; kk < 4; ++kk) {
            union { bf16x8 v; u16 s[8]; } u;
#pragma unroll
            for (int j = 0; j < 8; ++j)
                u.s[j] = f2bf(W[(size_t)(kk * 32 + quad * 8 + j) * NC + nt * 16 + r]);
            bf[nt][kk] = u.v;
        }
    float avs[NC / 16], avd[NC / 16], blv[NC / 16];
    if (EPI == 1) {
#pragma unroll
        for (int nt = 0; nt < NC / 16; ++nt) {
            avs[nt] = av_s[nt * 16 + r];
            avd[nt] = av_d[nt * 16 + r];
        }
    }
    if (EPI == 2) {
#pragma unroll
        for (int nt = 0; nt < NC / 16; ++nt) blv[nt] = bl[nt * 16 + r];
    }

    const int ntiles = (M + 15) >> 4;
    for (int t = gw; t < ntiles; t += nw) {
        const int row0 = t << 4;
        bf16x8 af[4];
        if (AF32) {
            const float* arow = (const float*)Ap + (size_t)(row0 + r) * 128;
#pragma unroll
            for (int kk = 0; kk < 4; ++kk) {
                f32x4 f0 = *reinterpret_cast<const f32x4*>(arow + kk * 32 + quad * 8);
                f32x4 f1 = *reinterpret_cast<const f32x4*>(arow + kk * 32 + quad * 8 + 4);
                union { bf16x8 v; u16 s[8]; } u;
#pragma unroll
                for (int j = 0; j < 4; ++j) { u.s[j] = f2bf(f0[j]); u.s[4 + j] = f2bf(f1[j]); }
                af[kk] = u.v;
            }
        } else {
            const u16* arow = (const u16*)Ap + (size_t)(row0 + r) * 128;
#pragma unroll
            for (int kk = 0; kk < 4; ++kk)
                af[kk] = *reinterpret_cast<const bf16x8*>(arow + kk * 32 + quad * 8);
        }
        f32x4 acc[NC / 16];
#pragma unroll
        for (int nt = 0; nt < NC / 16; ++nt) acc[nt] = (f32x4){0.f, 0.f, 0.f, 0.f};
#pragma unroll
        for (int kk = 0; kk < 4; ++kk)
#pragma unroll
            for (int nt = 0; nt < NC / 16; ++nt)
                acc[nt] = __builtin_amdgcn_mfma_f32_16x16x32_bf16(af[kk], bf[nt][kk],
                                                                  acc[nt], 0, 0, 0);
        if (EPI != 2) {
#pragma unroll
            for (int nt = 0; nt < NC / 16; ++nt)
#pragma unroll
                for (int reg = 0; reg < 4; ++reg)
                    Cout[(size_t)(row0 + quad * 4 + reg) * NC + nt * 16 + r] =
                        f2bf(acc[nt][reg]);
        }
        if (EPI == 1) {
            float ps[4] = {0.f, 0.f, 0.f, 0.f}, pd[4] = {0.f, 0.f, 0.f, 0.f};
#pragma unroll
            for (int nt = 0; nt < NC / 16; ++nt)
#pragma unroll
                for (int reg = 0; reg < 4; ++reg) {
                    ps[reg] += acc[nt][reg] * avs[nt];
                    pd[reg] += acc[nt][reg] * avd[nt];
                }
#pragma unroll
            for (int o = 1; o < 16; o <<= 1)
#pragma unroll
                for (int reg = 0; reg < 4; ++reg) {
                    ps[reg] += __shfl_xor(ps[reg], o);
                    pd[reg] += __shfl_xor(pd[reg], o);
                }
            if (r == 0) {
#pragma unroll
                for (int reg = 0; reg < 4; ++reg) {
                    ssrc[row0 + quad * 4 + reg] = ps[reg];
                    sdst[row0 + quad * 4 + reg] = pd[reg];
                }
            }
        }
        if (EPI == 2) {
#pragma unroll
            for (int reg = 0; reg < 4; ++reg) {
                float v[NC / 16];
                float m = -3.4e38f;
#pragma unroll
                for (int nt = 0; nt < NC / 16; ++nt) {
                    v[nt] = acc[nt][reg] + blv[nt];
                    m = fmaxf(m, v[nt]);
                }
#pragma unroll
                for (int o = 1; o < 16; o <<= 1) m = fmaxf(m, __shfl_xor(m, o));
                float s = 0.f;
#pragma unroll
                for (int nt = 0; nt < NC / 16; ++nt) s += __expf(v[nt] - m);
#pragma unroll
                for (int o = 1; o < 16; o <<= 1) s += __shfl_xor(s, o);
                float L = __logf(s);
                const size_t rb = (size_t)(row0 + quad * 4 + reg) * NC;
#pragma unroll
                for (int nt = 0; nt < NC / 16; ++nt)
                    outp[rb + nt * 16 + r] = v[nt] - m - L;
            }
        }
    }
}

// ---------------- SINGLE-PASS agg over CSR: 16-lane group per dst node.
// Deferred softmax (acc and sm unnormalized, scale at end). 8-edge batched
// main loop; bf16-truncated weights packed via v_perm feed v_dot2_f32_bf16.
// MODE 1: out = relu(acc/sm + b).  MODE 2: out = acc/sm + b + skip.
template <int MODE>
__global__ __launch_bounds__(256) void agg_fused(
    const int* __restrict__ rowptr, const int* __restrict__ col,
    const float* __restrict__ ssrc, const float* __restrict__ sdst,
    const u16* __restrict__ h, const float* __restrict__ b, const u16* __restrict__ skip,
    u16* __restrict__ out, int N) {
    const int lane = threadIdx.x & 63;
    const int gwave = (blockIdx.x * 256 + threadIdx.x) >> 6;
    const int grp = lane >> 4;
    const int ln = lane & 15;
    const int i = gwave * 4 + grp;
    if (i >= N) return;
    const int start = rowptr[i], end = rowptr[i + 1];
    const float sd = sdst[i];
    const size_t coff = (size_t)ln * 8;

    float acc[8] = {0.f, 0.f, 0.f, 0.f, 0.f, 0.f, 0.f, 0.f};
    float sm = 0.f;
    int e = start;
    for (; e + 8 <= end; e += 8) {
        int c[8];
#pragma unroll
        for (int q = 0; q < 8; ++q) c[q] = col[e + q];
        float s[8];
#pragma unroll
        for (int q = 0; q < 8; ++q) s[q] = ssrc[c[q]];
        union { u16x8 v; unsigned w[4]; } r[8];
#pragma unroll
        for (int q = 0; q < 8; ++q)
            r[q].v = *reinterpret_cast<const u16x8*>(h + (size_t)c[q] * 128 + coff);
        unsigned uu[8];
#pragma unroll
        for (int q = 0; q < 8; ++q) {
            float sc = s[q] + sd;
            sc = sc > 0.f ? sc : 0.2f * sc;
            float w = __expf(fminf(sc, 60.f));
            uu[q] = __float_as_uint(w) & 0xFFFF0000u;
            sm += __uint_as_float(uu[q]);
        }
#pragma unroll
        for (int p = 0; p < 4; ++p) {
            unsigned wp = __builtin_amdgcn_perm(uu[2 * p + 1], uu[2 * p], 0x07060302u);
#pragma unroll
            for (int jw = 0; jw < 4; ++jw) {
                unsigned lo = __builtin_amdgcn_perm(r[2 * p + 1].w[jw], r[2 * p].w[jw],
                                                    0x05040100u);
                unsigned hi = __builtin_amdgcn_perm(r[2 * p + 1].w[jw], r[2 * p].w[jw],
                                                    0x07060302u);
                asm("v_dot2_f32_bf16 %0, %1, %2, %0" : "+v"(acc[2 * jw]) : "v"(lo), "v"(wp));
                asm("v_dot2_f32_bf16 %0, %1, %2, %0"
                    : "+v"(acc[2 * jw + 1])
                    : "v"(hi), "v"(wp));
            }
        }
    }
    if (e + 4 <= end) {
        int c0 = col[e], c1 = col[e + 1], c2 = col[e + 2], c3 = col[e + 3];
        float s0 = ssrc[c0] + sd;
        float s1 = ssrc[c1] + sd;
        float s2 = ssrc[c2] + sd;
        float s3 = ssrc[c3] + sd;
        union { u16x8 v; unsigned w[4]; } r0, r1, r2, r3;
        r0.v = *reinterpret_cast<const u16x8*>(h + (size_t)c0 * 128 + coff);
        r1.v = *reinterpret_cast<const u16x8*>(h + (size_t)c1 * 128 + coff);
        r2.v = *reinterpret_cast<const u16x8*>(h + (size_t)c2 * 128 + coff);
        r3.v = *reinterpret_cast<const u16x8*>(h + (size_t)c3 * 128 + coff);
        s0 = s0 > 0.f ? s0 : 0.2f * s0;
        s1 = s1 > 0.f ? s1 : 0.2f * s1;
        s2 = s2 > 0.f ? s2 : 0.2f * s2;
        s3 = s3 > 0.f ? s3 : 0.2f * s3;
        float w0 = __expf(fminf(s0, 60.f));
        float w1 = __expf(fminf(s1, 60.f));
        float w2 = __expf(fminf(s2, 60.f));
        float w3 = __expf(fminf(s3, 60.f));
        unsigned u0 = __float_as_uint(w0) & 0xFFFF0000u;
        unsigned u1 = __float_as_uint(w1) & 0xFFFF0000u;
        unsigned u2 = __float_as_uint(w2) & 0xFFFF0000u;
        unsigned u3 = __float_as_uint(w3) & 0xFFFF0000u;
        sm += (__uint_as_float(u0) + __uint_as_float(u1)) +
              (__uint_as_float(u2) + __uint_as_float(u3));
        unsigned wp01 = __builtin_amdgcn_perm(u1, u0, 0x07060302u);
        unsigned wp23 = __builtin_amdgcn_perm(u3, u2, 0x07060302u);
#pragma unroll
        for (int jw = 0; jw < 4; ++jw) {
            unsigned lo01 = __builtin_amdgcn_perm(r1.w[jw], r0.w[jw], 0x05040100u);
            unsigned hi01 = __builtin_amdgcn_perm(r1.w[jw], r0.w[jw], 0x07060302u);
            unsigned lo23 = __builtin_amdgcn_perm(r3.w[jw], r2.w[jw], 0x05040100u);
            unsigned hi23 = __builtin_amdgcn_perm(r3.w[jw], r2.w[jw], 0x07060302u);
            asm("v_dot2_f32_bf16 %0, %1, %2, %0" : "+v"(acc[2 * jw]) : "v"(lo01), "v"(wp01));
            asm("v_dot2_f32_bf16 %0, %1, %2, %0" : "+v"(acc[2 * jw + 1]) : "v"(hi01), "v"(wp01));
            asm("v_dot2_f32_bf16 %0, %1, %2, %0" : "+v"(acc[2 * jw]) : "v"(lo23), "v"(wp23));
            asm("v_dot2_f32_bf16 %0, %1, %2, %0" : "+v"(acc[2 * jw + 1]) : "v"(hi23), "v"(wp23));
        }
        e += 4;
    }
    if (e + 2 <= end) {
        int c0 = col[e], c1 = col[e + 1];
        float s0 = ssrc[c0] + sd;
        float s1 = ssrc[c1] + sd;
        union { u16x8 v; unsigned w[4]; } r0, r1;
        r0.v = *reinterpret_cast<const u16x8*>(h + (size_t)c0 * 128 + coff);
        r1.v = *reinterpret_cast<const u16x8*>(h + (size_t)c1 * 128 + coff);
        s0 = s0 > 0.f ? s0 : 0.2f * s0;
        s1 = s1 > 0.f ? s1 : 0.2f * s1;
        float w0 = __expf(fminf(s0, 60.f));
        float w1 = __expf(fminf(s1, 60.f));
        unsigned u0 = __float_as_uint(w0) & 0xFFFF0000u;
        unsigned u1 = __float_as_uint(w1) & 0xFFFF0000u;
        sm += __uint_as_float(u0) + __uint_as_float(u1);
        unsigned wp01 = __builtin_amdgcn_perm(u1, u0, 0x07060302u);
#pragma unroll
        for (int jw = 0; jw < 4; ++jw) {
            unsigned lo01 = __builtin_amdgcn_perm(r1.w[jw], r0.w[jw], 0x05040100u);
            unsigned hi01 = __builtin_amdgcn_perm(r1.w[jw], r0.w[jw], 0x07060302u);
            asm("v_dot2_f32_bf16 %0, %1, %2, %0" : "+v"(acc[2 * jw]) : "v"(lo01), "v"(wp01));
            asm("v_dot2_f32_bf16 %0, %1, %2, %0" : "+v"(acc[2 * jw + 1]) : "v"(hi01), "v"(wp01));
        }
        e += 2;
    }
    if (e < end) {
        int c0 = col[e];
        float s0 = ssrc[c0] + sd;
        s0 = s0 > 0.f ? s0 : 0.2f * s0;
        float w0 = __expf(fminf(s0, 60.f));
        unsigned u0 = __float_as_uint(w0) & 0xFFFF0000u;
        float wt = __uint_as_float(u0);
        sm += wt;
        const u16x8 r0 = *reinterpret_cast<const u16x8*>(h + (size_t)c0 * 128 + coff);
#pragma unroll
        for (int j = 0; j < 8; ++j) acc[j] += wt * bf2f(r0[j]);
    }
    const float rd = 1.f / sm;

    u16x8 o;
    if (MODE == 1) {
#pragma unroll
        for (int j = 0; j < 8; ++j) {
            float v = acc[j] * rd + b[coff + j];
            v = v > 0.f ? v : 0.f;
            o[j] = f2bf(v);
        }
    } else {
        const u16x8 sk = *reinterpret_cast<const u16x8*>(skip + (size_t)i * 128 + coff);
#pragma unroll
        for (int j = 0; j < 8; ++j) {
            float v = acc[j] * rd + b[coff + j] + bf2f(sk[j]);
            o[j] = f2bf(v);
        }
    }
    *reinterpret_cast<u16x8*>(out + (size_t)i * 128 + coff) = o;
}

extern "C" void kernel_launch(void* const* d_in, const int* in_sizes, int n_in, void* d_out,
                              int out_size, void* d_ws, size_t ws_size, hipStream_t stream) {
    int ix = 0, iei = 1;
    if (in_sizes[0] < in_sizes[1]) { ix = 1; iei = 0; }
    const float* x = (const float*)d_in[ix];
    const int* ei = (const int*)d_in[iei];
    const float* W1 = (const float*)d_in[2];
    const float* a1s = (const float*)d_in[3];
    const float* a1d = (const float*)d_in[4];
    const float* b1 = (const float*)d_in[5];
    const float* W2 = (const float*)d_in[6];
    const float* a2s = (const float*)d_in[7];
    const float* a2d = (const float*)d_in[8];
    const float* b2 = (const float*)d_in[9];
    const float* Wl = (const float*)d_in[10];
    const float* bl = (const float*)d_in[11];

    const int N = in_sizes[ix] / 128;
    const int E = (out_size - N * 64) / 2;  // out = [logp N*64 | edge_index 2E], f32
    const int ET = E + N;
    const int K = (N + 127) >> 7;   // dst buckets of 128 nodes
    const int Mscan = K * GA;       // cntmat elements

    char* ws = (char*)d_ws;
    size_t off = 0;
    auto alloc = [&](size_t bytes) {
        void* p = ws + off;
        off += (bytes + 255) & ~(size_t)255;
        return p;
    };
    u16* h = (u16*)alloc((size_t)N * 128 * 2);   // bf16 gemm out / gather source
    u16* h1 = (u16*)alloc((size_t)N * 128 * 2);  // bf16 layer-1 activation (skip input)
    u16* o2 = (u16*)alloc((size_t)N * 128 * 2);  // bf16 layer-2 out (final gemm input)
    float* ssrc = (float*)alloc((size_t)N * 4);
    float* sdst = (float*)alloc((size_t)N * 4);
    int* eflag = (int*)alloc(256);
    int* cntmat = (int*)alloc((size_t)Mscan * 4);  // per-(bucket,block) counts -> offsets
    int* rowptr = (int*)alloc((size_t)(N + 1) * 4);
    int* bsum = (int*)alloc(4096);
    int* colv = (int*)alloc((size_t)ET * 4);
    // ebuf (partitioned packed edges, E u32) aliases h1: last read in csr_build,
    // h1 first written by agg_fused<1> afterwards (stream-ordered).
    unsigned* ebuf = (unsigned*)h1;

    float* out_logp = (float*)d_out;
    float* out_ei = out_logp + (size_t)N * 64;

    dim3 blk(256);
    const int ngrid4 = (N + 15) / 16;  // 16-lane group per node, 16 nodes/block
    const int nbx = (Mscan + SCHUNK - 1) / SCHUNK;
    const int G1 = 512;  // gemm blocks; +GA hist +GC copy = 1024 = 4 blocks/CU

    detect_kernel<<<1, 64, 0, stream>>>(ei, eflag);

    // ---- layer-1 GEMM (+scores) fused with bucket-count AND edge echo ----
    gemm_fused<128, true, 1, true><<<G1 + GA + GC, blk, 0, stream>>>(
        x, W1, h, N, a1s, a1d, ssrc, sdst, nullptr, nullptr, ei, eflag, cntmat, out_ei, 2 * E,
        E, ET, N, G1);

    // ---- exclusive scan of cntmat -> per-(bucket,block) offsets ----
    xscan_reduce<<<nbx, blk, 0, stream>>>(cntmat, bsum, Mscan);
    scan_mid_kernel<<<1, 64, 0, stream>>>(bsum, nbx);
    xscan_final<<<nbx, blk, 0, stream>>>(cntmat, bsum, Mscan);

    // ---- radix partition + per-bucket CSR build (LDS atomics only) ----
    partition_kernel<<<GA, blk, 0, stream>>>(ei, eflag, cntmat, ebuf, E, N);
    csr_build<<<K, blk, 0, stream>>>(ebuf, cntmat, rowptr, colv, E, N, ET);

    // ---- layer 1 aggregation (single-pass unnormalized + relu/bias) ----
    agg_fused<1><<<ngrid4, blk, 0, stream>>>(rowptr, colv, ssrc, sdst, h, b1, nullptr, h1, N);

    // ---- layer 2 ----
    gemm_fused<128, false, 1, false><<<G1, blk, 0, stream>>>(
        h1, W2, h, N, a2s, a2d, ssrc, sdst, nullptr, nullptr, nullptr, nullptr, nullptr,
        nullptr, 0, 0, 0, N, G1);
    agg_fused<2><<<ngrid4, blk, 0, stream>>>(rowptr, colv, ssrc, sdst, h, b2, h1, o2, N);

    // ---- final linear with fused log_softmax ----
    gemm_fused<64, false, 2, false><<<G1, blk, 0, stream>>>(
        o2, Wl, nullptr, N, nullptr, nullptr, nullptr, nullptr, bl, out_logp, nullptr, nullptr,
        nullptr, nullptr, 0, 0, 0, N, G1);
}